// Round 4
// baseline (502.075 us; speedup 1.0000x reference)
//
#include <hip/hip_runtime.h>
#include <cstddef>

// Problem constants (match reference)
constexpr int NN = 20000;    // nodes
constexpr int NE = 320000;   // edges
constexpr int NQ = 100000;   // queries
constexpr int DD = 256;      // feature dim

typedef __attribute__((ext_vector_type(8))) short bf16x8;
typedef __attribute__((ext_vector_type(4))) float f32x4;
typedef __attribute__((ext_vector_type(4))) unsigned short u16x4;

__device__ inline unsigned short f2bf(float f) {
    union { float f; unsigned u; } v; v.f = f;
    unsigned r = v.u + 0x7fffu + ((v.u >> 16) & 1u);   // RNE
    return (unsigned short)(r >> 16);
}
__device__ inline float bf2f(unsigned short h) {
    union { unsigned u; float f; } t; t.u = ((unsigned)h) << 16;
    return t.f;
}

// ---------------------------------------------------------------------------
// Degree histogram (int): deg[row[e]] += 1
__global__ __launch_bounds__(256) void k_deg(const int* __restrict__ row,
                                             int* __restrict__ deg) {
    int e = blockIdx.x * 256 + threadIdx.x;
    if (e < NE) atomicAdd(&deg[row[e]], 1);
}

// Single-block exclusive scan over deg -> offs[NN+1], cursor copy, recip.
__global__ __launch_bounds__(256) void k_scan(const int* __restrict__ deg,
                                              int* __restrict__ offs,
                                              int* __restrict__ cursor,
                                              float* __restrict__ recip) {
    __shared__ int wsum[4];
    __shared__ int s_carry;
    const int tid = threadIdx.x;
    const int wid = tid >> 6;
    const int lane = tid & 63;
    if (tid == 0) s_carry = 0;
    __syncthreads();
    for (int base = 0; base < NN; base += 256) {
        int i = base + tid;
        int v = (i < NN) ? deg[i] : 0;
        int sc = v;
#pragma unroll
        for (int d = 1; d < 64; d <<= 1) {
            int t = __shfl_up(sc, d);
            if (lane >= d) sc += t;
        }
        if (lane == 63) wsum[wid] = sc;
        __syncthreads();
        int wpre = 0;
        for (int w = 0; w < wid; ++w) wpre += wsum[w];
        int carry = s_carry;
        int incl = carry + wpre + sc;
        if (i < NN) {
            offs[i] = incl - v;
            cursor[i] = incl - v;
            recip[i] = 1.0f / fmaxf((float)v, 1.0f);
        }
        __syncthreads();
        if (tid == 255) s_carry = incl;
        __syncthreads();
    }
    if (tid == 0) offs[NN] = s_carry;
}

// Fill CSR adjacency: scol[cursor[row[e]]++] = col[e]
__global__ __launch_bounds__(256) void k_fill(const int* __restrict__ row,
                                              const int* __restrict__ col,
                                              int* __restrict__ cursor,
                                              int* __restrict__ scol) {
    int e = blockIdx.x * 256 + threadIdx.x;
    if (e < NE) {
        int r = row[e];
        int p = atomicAdd(&cursor[r], 1);
        scol[p] = col[e];
    }
}

// ---------------------------------------------------------------------------
// Gather-aggregate (mean): agg[i,:] = recip[i] * sum_{c in N(i)} x[c,:]
// One wave per node, 4-deep unrolled for outstanding loads.
__global__ __launch_bounds__(256) void k_agg(const int* __restrict__ offs,
                                             const int* __restrict__ scol,
                                             const float* __restrict__ recip,
                                             const float* __restrict__ x,
                                             float* __restrict__ agg) {
    int node = blockIdx.x * 4 + (threadIdx.x >> 6);
    int lane = threadIdx.x & 63;
    if (node >= NN) return;
    int s = offs[node];
    int e = offs[node + 1];
    float4 a0 = {0,0,0,0}, a1 = {0,0,0,0}, a2 = {0,0,0,0}, a3 = {0,0,0,0};
    int p = s;
    for (; p + 3 < e; p += 4) {
        int c0 = scol[p], c1 = scol[p+1], c2 = scol[p+2], c3 = scol[p+3];
        float4 v0 = *reinterpret_cast<const float4*>(x + (size_t)c0 * DD + lane * 4);
        float4 v1 = *reinterpret_cast<const float4*>(x + (size_t)c1 * DD + lane * 4);
        float4 v2 = *reinterpret_cast<const float4*>(x + (size_t)c2 * DD + lane * 4);
        float4 v3 = *reinterpret_cast<const float4*>(x + (size_t)c3 * DD + lane * 4);
        a0.x += v0.x; a0.y += v0.y; a0.z += v0.z; a0.w += v0.w;
        a1.x += v1.x; a1.y += v1.y; a1.z += v1.z; a1.w += v1.w;
        a2.x += v2.x; a2.y += v2.y; a2.z += v2.z; a2.w += v2.w;
        a3.x += v3.x; a3.y += v3.y; a3.z += v3.z; a3.w += v3.w;
    }
    for (; p < e; ++p) {
        int c0 = scol[p];
        float4 v0 = *reinterpret_cast<const float4*>(x + (size_t)c0 * DD + lane * 4);
        a0.x += v0.x; a0.y += v0.y; a0.z += v0.z; a0.w += v0.w;
    }
    float rc = recip[node];
    float4 o;
    o.x = (a0.x + a1.x + a2.x + a3.x) * rc;
    o.y = (a0.y + a1.y + a2.y + a3.y) * rc;
    o.z = (a0.z + a1.z + a2.z + a3.z) * rc;
    o.w = (a0.w + a1.w + a2.w + a3.w) * rc;
    *reinterpret_cast<float4*>(agg + (size_t)node * DD + lane * 4) = o;
}

// ---------------------------------------------------------------------------
// Pack one 256x256 f32 matrix into bf16 MFMA B-fragment layout, hi + lo split.
// Fragment t = kt*16+nt; P[(t*64+lane)*8 + i] = bf16 of W[kt*32+(lane>>4)*8+i][nt*16+(lane&15)]
// 4 matrices fused: blockIdx.x>>5 selects the matrix.
__global__ __launch_bounds__(256) void k_packs(
    const float* __restrict__ w0, const float* __restrict__ w1,
    const float* __restrict__ w2, const float* __restrict__ w3,
    unsigned short* __restrict__ h0, unsigned short* __restrict__ h1,
    unsigned short* __restrict__ h2, unsigned short* __restrict__ h3,
    unsigned short* __restrict__ l0, unsigned short* __restrict__ l1,
    unsigned short* __restrict__ l2, unsigned short* __restrict__ l3) {
    int m = blockIdx.x >> 5;
    int idx = (blockIdx.x & 31) * 256 + threadIdx.x;   // 0..8191
    const float* W = (m == 0) ? w0 : (m == 1) ? w1 : (m == 2) ? w2 : w3;
    unsigned short* H = (m == 0) ? h0 : (m == 1) ? h1 : (m == 2) ? h2 : h3;
    unsigned short* L = (m == 0) ? l0 : (m == 1) ? l1 : (m == 2) ? l2 : l3;
    int t = idx >> 6, lane = idx & 63;
    int kt = t >> 4, nt = t & 15;
    int k0 = kt * 32 + (lane >> 4) * 8;
    int n = nt * 16 + (lane & 15);
    unsigned uh[4], ul[4];
#pragma unroll
    for (int i = 0; i < 4; ++i) {
        float fa = W[(size_t)(k0 + 2 * i) * DD + n];
        float fb = W[(size_t)(k0 + 2 * i + 1) * DD + n];
        unsigned short ha = f2bf(fa), hb = f2bf(fb);
        unsigned short la = f2bf(fa - bf2f(ha)), lb = f2bf(fb - bf2f(hb));
        uh[i] = (unsigned)ha | ((unsigned)hb << 16);
        ul[i] = (unsigned)la | ((unsigned)lb << 16);
    }
    *reinterpret_cast<uint4*>(H + (size_t)idx * 8) = make_uint4(uh[0], uh[1], uh[2], uh[3]);
    *reinterpret_cast<uint4*>(L + (size_t)idx * 8) = make_uint4(ul[0], ul[1], ul[2], ul[3]);
}

// Pack Wp1 (hi only) for the predictor.
__global__ __launch_bounds__(256) void k_pack(const float* __restrict__ W,
                                              unsigned short* __restrict__ P) {
    int idx = blockIdx.x * 256 + threadIdx.x;
    if (idx >= 128 * 64) return;
    int t = idx >> 6, lane = idx & 63;
    int kt = t >> 4, nt = t & 15;
    int k0 = kt * 32 + (lane >> 4) * 8;
    int n = nt * 16 + (lane & 15);
    unsigned w[4];
#pragma unroll
    for (int i = 0; i < 4; ++i) {
        unsigned lo = f2bf(W[(size_t)(k0 + 2 * i) * DD + n]);
        unsigned hi = f2bf(W[(size_t)(k0 + 2 * i + 1) * DD + n]);
        w[i] = lo | (hi << 16);
    }
    *reinterpret_cast<uint4*>(P + (size_t)idx * 8) = make_uint4(w[0], w[1], w[2], w[3]);
}

// ---------------------------------------------------------------------------
// Split-bf16 A-fragment conversion: 8 consecutive f32 -> hi/lo bf16x8
__device__ inline void cvt8(const float* __restrict__ p, bf16x8& h, bf16x8& l) {
    float4 f0 = *reinterpret_cast<const float4*>(p);
    float4 f1 = *reinterpret_cast<const float4*>(p + 4);
    float fv[8] = {f0.x, f0.y, f0.z, f0.w, f1.x, f1.y, f1.z, f1.w};
#pragma unroll
    for (int i = 0; i < 8; ++i) {
        unsigned short hb = f2bf(fv[i]);
        h[i] = (short)hb;
        l[i] = (short)f2bf(fv[i] - bf2f(hb));
    }
}

// ---------------------------------------------------------------------------
// MFMA SAGE layer: out = [relu]( A0 @ Wl + b + A1 @ Wr ), split-bf16 (3 terms).
// Block: 4 waves x 32 rows = 128 rows. Wave: two 16-row M-tiles, N=256 (16 nt).
// out may alias A0/A1 (rows are block-private; reads precede epilogue writes).
template <int RELU>
__global__ __launch_bounds__(256) void k_sagem(
    const float* __restrict__ A0, const float* __restrict__ A1,
    const unsigned short* __restrict__ Wlh, const unsigned short* __restrict__ Wll,
    const unsigned short* __restrict__ Wrh, const unsigned short* __restrict__ Wrl,
    const float* __restrict__ b, float* __restrict__ out) {
    const int wave = threadIdx.x >> 6;
    const int lane = threadIdx.x & 63;
    const int w0 = blockIdx.x * 128 + wave * 32;
    const int kcol = (lane >> 4) * 8;
    const int ar0 = min(w0 + (lane & 15), NN - 1);
    const int ar1 = min(w0 + 16 + (lane & 15), NN - 1);

    f32x4 acc0[16], acc1[16];
#pragma unroll
    for (int nt = 0; nt < 16; ++nt) {
        acc0[nt] = {0, 0, 0, 0};
        acc1[nt] = {0, 0, 0, 0};
    }

#pragma unroll
    for (int src = 0; src < 2; ++src) {
        const float* A = src ? A1 : A0;
        const unsigned short* Bh = src ? Wrh : Wlh;
        const unsigned short* Bl = src ? Wrl : Wll;
#pragma unroll 2
        for (int kt = 0; kt < 8; ++kt) {
            bf16x8 ah0, al0, ah1, al1;
            cvt8(A + (size_t)ar0 * DD + kt * 32 + kcol, ah0, al0);
            cvt8(A + (size_t)ar1 * DD + kt * 32 + kcol, ah1, al1);
#pragma unroll
            for (int nt = 0; nt < 16; ++nt) {
                const size_t fo = ((size_t)((kt * 16 + nt) * 64 + lane)) * 8;
                bf16x8 bh = *reinterpret_cast<const bf16x8*>(Bh + fo);
                bf16x8 bl = *reinterpret_cast<const bf16x8*>(Bl + fo);
                acc0[nt] = __builtin_amdgcn_mfma_f32_16x16x32_bf16(ah0, bh, acc0[nt], 0, 0, 0);
                acc1[nt] = __builtin_amdgcn_mfma_f32_16x16x32_bf16(ah1, bh, acc1[nt], 0, 0, 0);
                acc0[nt] = __builtin_amdgcn_mfma_f32_16x16x32_bf16(al0, bh, acc0[nt], 0, 0, 0);
                acc1[nt] = __builtin_amdgcn_mfma_f32_16x16x32_bf16(al1, bh, acc1[nt], 0, 0, 0);
                acc0[nt] = __builtin_amdgcn_mfma_f32_16x16x32_bf16(ah0, bl, acc0[nt], 0, 0, 0);
                acc1[nt] = __builtin_amdgcn_mfma_f32_16x16x32_bf16(ah1, bl, acc1[nt], 0, 0, 0);
            }
        }
    }

    // Epilogue: bias (+relu) + store. acc[nt][j]: row=(lane>>4)*4+j, col=lane&15.
    const int n0 = lane & 15;
    const int rg = (lane >> 4) * 4;
#pragma unroll
    for (int nt = 0; nt < 16; ++nt) {
        int n = nt * 16 + n0;
        float bias = b[n];
#pragma unroll
        for (int j = 0; j < 4; ++j) {
            int r0 = w0 + rg + j;
            if (r0 < NN) {
                float v = acc0[nt][j] + bias;
                if (RELU) v = fmaxf(v, 0.0f);
                out[(size_t)r0 * DD + n] = v;
            }
            int r1 = w0 + 16 + rg + j;
            if (r1 < NN) {
                float v = acc1[nt][j] + bias;
                if (RELU) v = fmaxf(v, 0.0f);
                out[(size_t)r1 * DD + n] = v;
            }
        }
    }
}

// ---------------------------------------------------------------------------
// Predictor with bf16 MFMA GEMM, fp32 accumulate.
__global__ __launch_bounds__(256) void k_pred(const int* __restrict__ edges,
                                              const float* __restrict__ x2,
                                              const unsigned short* __restrict__ Wp1p,
                                              const float* __restrict__ bp1,
                                              const float* __restrict__ Wp2,
                                              const float* __restrict__ bp2,
                                              float* __restrict__ out) {
    __shared__ unsigned short sh[64][264];   // bf16 h tile, padded stride
    const int tid = threadIdx.x;
    const int wave = tid >> 6;
    const int lane = tid & 63;
    const int q0 = blockIdx.x * 64;

    for (int s = 0; s < 16; ++s) {
        int r = wave * 16 + s;
        int q = q0 + r;
        float4 pa = {0, 0, 0, 0}, pb = {0, 0, 0, 0};
        if (q < NQ) {
            int a = edges[q];
            int c = edges[NQ + q];
            pa = *reinterpret_cast<const float4*>(x2 + (size_t)a * DD + lane * 4);
            pb = *reinterpret_cast<const float4*>(x2 + (size_t)c * DD + lane * 4);
        }
        u16x4 pk;
        pk[0] = f2bf(pa.x * pb.x);
        pk[1] = f2bf(pa.y * pb.y);
        pk[2] = f2bf(pa.z * pb.z);
        pk[3] = f2bf(pa.w * pb.w);
        *reinterpret_cast<u16x4*>(&sh[r][lane * 4]) = pk;
    }
    __syncthreads();

    f32x4 acc[16];
#pragma unroll
    for (int nt = 0; nt < 16; ++nt) acc[nt] = {0, 0, 0, 0};

    const int arow = wave * 16 + (lane & 15);
    const int akoff = (lane >> 4) * 8;
    for (int kt = 0; kt < 8; ++kt) {
        bf16x8 afrag = *reinterpret_cast<const bf16x8*>(&sh[arow][kt * 32 + akoff]);
#pragma unroll
        for (int nt = 0; nt < 16; ++nt) {
            bf16x8 bfrag = *reinterpret_cast<const bf16x8*>(
                Wp1p + ((size_t)((kt * 16 + nt) * 64 + lane)) * 8);
            acc[nt] = __builtin_amdgcn_mfma_f32_16x16x32_bf16(afrag, bfrag, acc[nt], 0, 0, 0);
        }
    }

    float rowsum[4] = {0, 0, 0, 0};
#pragma unroll
    for (int nt = 0; nt < 16; ++nt) {
        int n = nt * 16 + (lane & 15);
        float bias = bp1[n];
        float w2 = Wp2[n];
#pragma unroll
        for (int j = 0; j < 4; ++j) {
            float v = fmaxf(acc[nt][j] + bias, 0.0f);
            rowsum[j] += v * w2;
        }
    }
#pragma unroll
    for (int m = 1; m < 16; m <<= 1) {
#pragma unroll
        for (int j = 0; j < 4; ++j) rowsum[j] += __shfl_xor(rowsum[j], m);
    }
    if ((lane & 15) == 0) {
        float b2v = bp2[0];
#pragma unroll
        for (int j = 0; j < 4; ++j) {
            int q = q0 + wave * 16 + (lane >> 4) * 4 + j;
            if (q < NQ) {
                float z = rowsum[j] + b2v;
                out[q] = 1.0f / (1.0f + expf(-z));
            }
        }
    }
}

// ---------------------------------------------------------------------------
extern "C" void kernel_launch(void* const* d_in, const int* in_sizes, int n_in,
                              void* d_out, int out_size, void* d_ws, size_t ws_size,
                              hipStream_t stream) {
    const int*   adj_row = (const int*)d_in[0];
    const int*   adj_col = (const int*)d_in[1];
    const int*   edges   = (const int*)d_in[2];
    const float* emb     = (const float*)d_in[3];
    const float* W1l     = (const float*)d_in[4];
    const float* b1      = (const float*)d_in[5];
    const float* W1r     = (const float*)d_in[6];
    const float* W2l     = (const float*)d_in[7];
    const float* b2      = (const float*)d_in[8];
    const float* W2r     = (const float*)d_in[9];
    const float* Wp1     = (const float*)d_in[10];
    const float* bp1     = (const float*)d_in[11];
    const float* Wp2     = (const float*)d_in[12];
    const float* bp2     = (const float*)d_in[13];
    float* out = (float*)d_out;

    // Workspace layout
    char* ws = (char*)d_ws;
    size_t off = 0;
    float* agg    = (float*)(ws + off); off += (size_t)NN * DD * 4;   // 20.48 MB
    float* x1     = (float*)(ws + off); off += (size_t)NN * DD * 4;   // 20.48 MB
    int*   deg    = (int*)(ws + off);   off += (size_t)NN * 4;
    int*   offs   = (int*)(ws + off);   off += (size_t)(NN + 1) * 4;
    int*   cursor = (int*)(ws + off);   off += (size_t)NN * 4;
    float* recip  = (float*)(ws + off); off += (size_t)NN * 4;
    int*   scol   = (int*)(ws + off);   off += (size_t)NE * 4;        // 1.28 MB
    unsigned short* Wp1p = (unsigned short*)(ws + off); off += (size_t)DD * DD * 2;
    unsigned short* pk[8];   // W1l,W1r,W2l,W2r x {hi,lo}
    for (int i = 0; i < 8; ++i) { pk[i] = (unsigned short*)(ws + off); off += (size_t)DD * DD * 2; }
    float* x2 = agg;  // layer-2 output aliases agg (block-private rows)

    // Build CSR + pack weights
    hipMemsetAsync(deg, 0, NN * 4, stream);
    k_deg<<<(NE + 255) / 256, 256, 0, stream>>>(adj_row, deg);
    k_scan<<<1, 256, 0, stream>>>(deg, offs, cursor, recip);
    k_fill<<<(NE + 255) / 256, 256, 0, stream>>>(adj_row, adj_col, cursor, scol);
    k_pack<<<32, 256, 0, stream>>>(Wp1, Wp1p);
    k_packs<<<128, 256, 0, stream>>>(W1l, W1r, W2l, W2r,
                                     pk[0], pk[2], pk[4], pk[6],
                                     pk[1], pk[3], pk[5], pk[7]);

    // Layer 1
    k_agg<<<(NN + 3) / 4, 256, 0, stream>>>(offs, scol, recip, emb, agg);
    k_sagem<1><<<(NN + 127) / 128, 256, 0, stream>>>(agg, emb,
                                                     pk[0], pk[1], pk[2], pk[3],
                                                     b1, x1);

    // Layer 2 (output aliases agg)
    k_agg<<<(NN + 3) / 4, 256, 0, stream>>>(offs, scol, recip, x1, agg);
    k_sagem<0><<<(NN + 127) / 128, 256, 0, stream>>>(agg, x1,
                                                     pk[4], pk[5], pk[6], pk[7],
                                                     b2, x2);

    // Predictor (bf16 MFMA)
    k_pred<<<(NQ + 63) / 64, 256, 0, stream>>>(edges, x2, Wp1p, bp1, Wp2, bp2, out);
}

// Round 5
// 395.693 us; speedup vs baseline: 1.2688x; 1.2688x over previous
//
#include <hip/hip_runtime.h>
#include <cstddef>

// Problem constants (match reference)
constexpr int NN = 20000;    // nodes
constexpr int NE = 320000;   // edges
constexpr int NQ = 100000;   // queries
constexpr int DD = 256;      // feature dim

typedef __attribute__((ext_vector_type(8))) short bf16x8;
typedef __attribute__((ext_vector_type(4))) float f32x4;
typedef __attribute__((ext_vector_type(4))) unsigned short u16x4;

__device__ inline unsigned short f2bf(float f) {
    union { float f; unsigned u; } v; v.f = f;
    unsigned r = v.u + 0x7fffu + ((v.u >> 16) & 1u);   // RNE
    return (unsigned short)(r >> 16);
}
__device__ inline float bf2f(unsigned short h) {
    union { unsigned u; float f; } t; t.u = ((unsigned)h) << 16;
    return t.f;
}

// ---------------------------------------------------------------------------
// Degree histogram (int): deg[row[e]] += 1
__global__ __launch_bounds__(256) void k_deg(const int* __restrict__ row,
                                             int* __restrict__ deg) {
    int e = blockIdx.x * 256 + threadIdx.x;
    if (e < NE) atomicAdd(&deg[row[e]], 1);
}

// Single-block exclusive scan over deg -> offs[NN+1], cursor copy, recip.
__global__ __launch_bounds__(256) void k_scan(const int* __restrict__ deg,
                                              int* __restrict__ offs,
                                              int* __restrict__ cursor,
                                              float* __restrict__ recip) {
    __shared__ int wsum[4];
    __shared__ int s_carry;
    const int tid = threadIdx.x;
    const int wid = tid >> 6;
    const int lane = tid & 63;
    if (tid == 0) s_carry = 0;
    __syncthreads();
    for (int base = 0; base < NN; base += 256) {
        int i = base + tid;
        int v = (i < NN) ? deg[i] : 0;
        int sc = v;
#pragma unroll
        for (int d = 1; d < 64; d <<= 1) {
            int t = __shfl_up(sc, d);
            if (lane >= d) sc += t;
        }
        if (lane == 63) wsum[wid] = sc;
        __syncthreads();
        int wpre = 0;
        for (int w = 0; w < wid; ++w) wpre += wsum[w];
        int carry = s_carry;
        int incl = carry + wpre + sc;
        if (i < NN) {
            offs[i] = incl - v;
            cursor[i] = incl - v;
            recip[i] = 1.0f / fmaxf((float)v, 1.0f);
        }
        __syncthreads();
        if (tid == 255) s_carry = incl;
        __syncthreads();
    }
    if (tid == 0) offs[NN] = s_carry;
}

// Fill CSR adjacency: scol[cursor[row[e]]++] = col[e]
__global__ __launch_bounds__(256) void k_fill(const int* __restrict__ row,
                                              const int* __restrict__ col,
                                              int* __restrict__ cursor,
                                              int* __restrict__ scol) {
    int e = blockIdx.x * 256 + threadIdx.x;
    if (e < NE) {
        int r = row[e];
        int p = atomicAdd(&cursor[r], 1);
        scol[p] = col[e];
    }
}

// ---------------------------------------------------------------------------
// Gather-aggregate (mean): agg[i,:] = recip[i] * sum_{c in N(i)} x[c,:]
__global__ __launch_bounds__(256) void k_agg(const int* __restrict__ offs,
                                             const int* __restrict__ scol,
                                             const float* __restrict__ recip,
                                             const float* __restrict__ x,
                                             float* __restrict__ agg) {
    int node = blockIdx.x * 4 + (threadIdx.x >> 6);
    int lane = threadIdx.x & 63;
    if (node >= NN) return;
    int s = offs[node];
    int e = offs[node + 1];
    float4 a0 = {0,0,0,0}, a1 = {0,0,0,0}, a2 = {0,0,0,0}, a3 = {0,0,0,0};
    int p = s;
    for (; p + 3 < e; p += 4) {
        int c0 = scol[p], c1 = scol[p+1], c2 = scol[p+2], c3 = scol[p+3];
        float4 v0 = *reinterpret_cast<const float4*>(x + (size_t)c0 * DD + lane * 4);
        float4 v1 = *reinterpret_cast<const float4*>(x + (size_t)c1 * DD + lane * 4);
        float4 v2 = *reinterpret_cast<const float4*>(x + (size_t)c2 * DD + lane * 4);
        float4 v3 = *reinterpret_cast<const float4*>(x + (size_t)c3 * DD + lane * 4);
        a0.x += v0.x; a0.y += v0.y; a0.z += v0.z; a0.w += v0.w;
        a1.x += v1.x; a1.y += v1.y; a1.z += v1.z; a1.w += v1.w;
        a2.x += v2.x; a2.y += v2.y; a2.z += v2.z; a2.w += v2.w;
        a3.x += v3.x; a3.y += v3.y; a3.z += v3.z; a3.w += v3.w;
    }
    for (; p < e; ++p) {
        int c0 = scol[p];
        float4 v0 = *reinterpret_cast<const float4*>(x + (size_t)c0 * DD + lane * 4);
        a0.x += v0.x; a0.y += v0.y; a0.z += v0.z; a0.w += v0.w;
    }
    float rc = recip[node];
    float4 o;
    o.x = (a0.x + a1.x + a2.x + a3.x) * rc;
    o.y = (a0.y + a1.y + a2.y + a3.y) * rc;
    o.z = (a0.z + a1.z + a2.z + a3.z) * rc;
    o.w = (a0.w + a1.w + a2.w + a3.w) * rc;
    *reinterpret_cast<float4*>(agg + (size_t)node * DD + lane * 4) = o;
}

// ---------------------------------------------------------------------------
// Pack one 256x256 f32 matrix into bf16 MFMA B-fragment layout, hi + lo split.
__global__ __launch_bounds__(256) void k_packs(
    const float* __restrict__ w0, const float* __restrict__ w1,
    const float* __restrict__ w2, const float* __restrict__ w3,
    unsigned short* __restrict__ h0, unsigned short* __restrict__ h1,
    unsigned short* __restrict__ h2, unsigned short* __restrict__ h3,
    unsigned short* __restrict__ l0, unsigned short* __restrict__ l1,
    unsigned short* __restrict__ l2, unsigned short* __restrict__ l3) {
    int m = blockIdx.x >> 5;
    int idx = (blockIdx.x & 31) * 256 + threadIdx.x;   // 0..8191
    const float* W = (m == 0) ? w0 : (m == 1) ? w1 : (m == 2) ? w2 : w3;
    unsigned short* H = (m == 0) ? h0 : (m == 1) ? h1 : (m == 2) ? h2 : h3;
    unsigned short* L = (m == 0) ? l0 : (m == 1) ? l1 : (m == 2) ? l2 : l3;
    int t = idx >> 6, lane = idx & 63;
    int kt = t >> 4, nt = t & 15;
    int k0 = kt * 32 + (lane >> 4) * 8;
    int n = nt * 16 + (lane & 15);
    unsigned uh[4], ul[4];
#pragma unroll
    for (int i = 0; i < 4; ++i) {
        float fa = W[(size_t)(k0 + 2 * i) * DD + n];
        float fb = W[(size_t)(k0 + 2 * i + 1) * DD + n];
        unsigned short ha = f2bf(fa), hb = f2bf(fb);
        unsigned short la = f2bf(fa - bf2f(ha)), lb = f2bf(fb - bf2f(hb));
        uh[i] = (unsigned)ha | ((unsigned)hb << 16);
        ul[i] = (unsigned)la | ((unsigned)lb << 16);
    }
    *reinterpret_cast<uint4*>(H + (size_t)idx * 8) = make_uint4(uh[0], uh[1], uh[2], uh[3]);
    *reinterpret_cast<uint4*>(L + (size_t)idx * 8) = make_uint4(ul[0], ul[1], ul[2], ul[3]);
}

// Pack Wp1 (hi only) for the predictor.
__global__ __launch_bounds__(256) void k_pack(const float* __restrict__ W,
                                              unsigned short* __restrict__ P) {
    int idx = blockIdx.x * 256 + threadIdx.x;
    if (idx >= 128 * 64) return;
    int t = idx >> 6, lane = idx & 63;
    int kt = t >> 4, nt = t & 15;
    int k0 = kt * 32 + (lane >> 4) * 8;
    int n = nt * 16 + (lane & 15);
    unsigned w[4];
#pragma unroll
    for (int i = 0; i < 4; ++i) {
        unsigned lo = f2bf(W[(size_t)(k0 + 2 * i) * DD + n]);
        unsigned hi = f2bf(W[(size_t)(k0 + 2 * i + 1) * DD + n]);
        w[i] = lo | (hi << 16);
    }
    *reinterpret_cast<uint4*>(P + (size_t)idx * 8) = make_uint4(w[0], w[1], w[2], w[3]);
}

// ---------------------------------------------------------------------------
// Split-bf16 A-fragment conversion: 8 consecutive f32 -> hi/lo bf16x8
__device__ inline void cvt8(const float* __restrict__ p, bf16x8& h, bf16x8& l) {
    float4 f0 = *reinterpret_cast<const float4*>(p);
    float4 f1 = *reinterpret_cast<const float4*>(p + 4);
    float fv[8] = {f0.x, f0.y, f0.z, f0.w, f1.x, f1.y, f1.z, f1.w};
#pragma unroll
    for (int i = 0; i < 8; ++i) {
        unsigned short hb = f2bf(fv[i]);
        h[i] = (short)hb;
        l[i] = (short)f2bf(fv[i] - bf2f(hb));
    }
}

// ---------------------------------------------------------------------------
// MFMA SAGE layer: out = [relu]( A0 @ Wl + b + A1 @ Wr ), split-bf16 (3 terms).
// Wave = one 16-row M-tile x (NSPLIT ? 128 : 256) cols. Block = 4 waves = 64 rows.
// NSPLIT=1: blockIdx = mblk*2 + nhalf, out must NOT alias A0/A1.
// NSPLIT=0: full N per block; out may alias A0/A1 (block-private rows).
template <int RELU, int NSPLIT>
__global__ __launch_bounds__(256) void k_sagem(
    const float* __restrict__ A0, const float* __restrict__ A1,
    const unsigned short* __restrict__ Wlh, const unsigned short* __restrict__ Wll,
    const unsigned short* __restrict__ Wrh, const unsigned short* __restrict__ Wrl,
    const float* __restrict__ b, float* __restrict__ out) {
    constexpr int NT = NSPLIT ? 8 : 16;
    const int nh   = NSPLIT ? (blockIdx.x & 1) : 0;
    const int mblk = NSPLIT ? (blockIdx.x >> 1) : blockIdx.x;
    const int wave = threadIdx.x >> 6;
    const int lane = threadIdx.x & 63;
    const int row0 = mblk * 64 + wave * 16;
    const int kcol = (lane >> 4) * 8;
    const int ar = min(row0 + (lane & 15), NN - 1);

    f32x4 acc[NT];
#pragma unroll
    for (int nt = 0; nt < NT; ++nt) acc[nt] = {0, 0, 0, 0};

#pragma unroll
    for (int src = 0; src < 2; ++src) {
        const float* A = src ? A1 : A0;
        const unsigned short* Bh = src ? Wrh : Wlh;
        const unsigned short* Bl = src ? Wrl : Wll;
#pragma unroll 2
        for (int kt = 0; kt < 8; ++kt) {
            bf16x8 ah, al;
            cvt8(A + (size_t)ar * DD + kt * 32 + kcol, ah, al);
#pragma unroll
            for (int nt = 0; nt < NT; ++nt) {
                const size_t fo = ((size_t)((kt * 16 + nh * 8 + nt) * 64 + lane)) * 8;
                bf16x8 bh = *reinterpret_cast<const bf16x8*>(Bh + fo);
                bf16x8 bl = *reinterpret_cast<const bf16x8*>(Bl + fo);
                acc[nt] = __builtin_amdgcn_mfma_f32_16x16x32_bf16(ah, bh, acc[nt], 0, 0, 0);
                acc[nt] = __builtin_amdgcn_mfma_f32_16x16x32_bf16(al, bh, acc[nt], 0, 0, 0);
                acc[nt] = __builtin_amdgcn_mfma_f32_16x16x32_bf16(ah, bl, acc[nt], 0, 0, 0);
            }
        }
    }

    // Epilogue: bias (+relu) + store. acc[nt][j]: row=(lane>>4)*4+j, col=lane&15.
    const int n0 = lane & 15;
    const int rg = (lane >> 4) * 4;
#pragma unroll
    for (int nt = 0; nt < NT; ++nt) {
        int n = (nh * 8 + nt) * 16 + n0;
        float bias = b[n];
#pragma unroll
        for (int j = 0; j < 4; ++j) {
            int r = row0 + rg + j;
            if (r < NN) {
                float v = acc[nt][j] + bias;
                if (RELU) v = fmaxf(v, 0.0f);
                out[(size_t)r * DD + n] = v;
            }
        }
    }
}

// ---------------------------------------------------------------------------
// Predictor with bf16 MFMA GEMM, fp32 accumulate.
__global__ __launch_bounds__(256) void k_pred(const int* __restrict__ edges,
                                              const float* __restrict__ x2,
                                              const unsigned short* __restrict__ Wp1p,
                                              const float* __restrict__ bp1,
                                              const float* __restrict__ Wp2,
                                              const float* __restrict__ bp2,
                                              float* __restrict__ out) {
    __shared__ unsigned short sh[64][264];   // bf16 h tile, padded stride
    const int tid = threadIdx.x;
    const int wave = tid >> 6;
    const int lane = tid & 63;
    const int q0 = blockIdx.x * 64;

    for (int s = 0; s < 16; ++s) {
        int r = wave * 16 + s;
        int q = q0 + r;
        float4 pa = {0, 0, 0, 0}, pb = {0, 0, 0, 0};
        if (q < NQ) {
            int a = edges[q];
            int c = edges[NQ + q];
            pa = *reinterpret_cast<const float4*>(x2 + (size_t)a * DD + lane * 4);
            pb = *reinterpret_cast<const float4*>(x2 + (size_t)c * DD + lane * 4);
        }
        u16x4 pk;
        pk[0] = f2bf(pa.x * pb.x);
        pk[1] = f2bf(pa.y * pb.y);
        pk[2] = f2bf(pa.z * pb.z);
        pk[3] = f2bf(pa.w * pb.w);
        *reinterpret_cast<u16x4*>(&sh[r][lane * 4]) = pk;
    }
    __syncthreads();

    f32x4 acc[16];
#pragma unroll
    for (int nt = 0; nt < 16; ++nt) acc[nt] = {0, 0, 0, 0};

    const int arow = wave * 16 + (lane & 15);
    const int akoff = (lane >> 4) * 8;
    for (int kt = 0; kt < 8; ++kt) {
        bf16x8 afrag = *reinterpret_cast<const bf16x8*>(&sh[arow][kt * 32 + akoff]);
#pragma unroll
        for (int nt = 0; nt < 16; ++nt) {
            bf16x8 bfrag = *reinterpret_cast<const bf16x8*>(
                Wp1p + ((size_t)((kt * 16 + nt) * 64 + lane)) * 8);
            acc[nt] = __builtin_amdgcn_mfma_f32_16x16x32_bf16(afrag, bfrag, acc[nt], 0, 0, 0);
        }
    }

    float rowsum[4] = {0, 0, 0, 0};
#pragma unroll
    for (int nt = 0; nt < 16; ++nt) {
        int n = nt * 16 + (lane & 15);
        float bias = bp1[n];
        float w2 = Wp2[n];
#pragma unroll
        for (int j = 0; j < 4; ++j) {
            float v = fmaxf(acc[nt][j] + bias, 0.0f);
            rowsum[j] += v * w2;
        }
    }
#pragma unroll
    for (int m = 1; m < 16; m <<= 1) {
#pragma unroll
        for (int j = 0; j < 4; ++j) rowsum[j] += __shfl_xor(rowsum[j], m);
    }
    if ((lane & 15) == 0) {
        float b2v = bp2[0];
#pragma unroll
        for (int j = 0; j < 4; ++j) {
            int q = q0 + wave * 16 + (lane >> 4) * 4 + j;
            if (q < NQ) {
                float z = rowsum[j] + b2v;
                out[q] = 1.0f / (1.0f + expf(-z));
            }
        }
    }
}

// ---------------------------------------------------------------------------
extern "C" void kernel_launch(void* const* d_in, const int* in_sizes, int n_in,
                              void* d_out, int out_size, void* d_ws, size_t ws_size,
                              hipStream_t stream) {
    const int*   adj_row = (const int*)d_in[0];
    const int*   adj_col = (const int*)d_in[1];
    const int*   edges   = (const int*)d_in[2];
    const float* emb     = (const float*)d_in[3];
    const float* W1l     = (const float*)d_in[4];
    const float* b1      = (const float*)d_in[5];
    const float* W1r     = (const float*)d_in[6];
    const float* W2l     = (const float*)d_in[7];
    const float* b2      = (const float*)d_in[8];
    const float* W2r     = (const float*)d_in[9];
    const float* Wp1     = (const float*)d_in[10];
    const float* bp1     = (const float*)d_in[11];
    const float* Wp2     = (const float*)d_in[12];
    const float* bp2     = (const float*)d_in[13];
    float* out = (float*)d_out;

    const size_t featBytes = (size_t)NN * DD * 4;   // 20.48 MB
    const size_t packBytes = (size_t)DD * DD * 2;   // 128 KB

    // Does ws fit a third feature buffer (x2 separate from agg)?
    const size_t needBig = 3 * featBytes + 4 * (size_t)NN * 4 + 16 +
                           (size_t)NE * 4 + 9 * packBytes;
    const bool big = (ws_size >= needBig);

    char* ws = (char*)d_ws;
    size_t off = 0;
    float* agg = (float*)(ws + off); off += featBytes;
    float* x1  = (float*)(ws + off); off += featBytes;
    float* x2  = agg;
    if (big) { x2 = (float*)(ws + off); off += featBytes; }
    int*   deg    = (int*)(ws + off);   off += (size_t)NN * 4;
    int*   offs   = (int*)(ws + off);   off += (size_t)(NN + 1) * 4;
    int*   cursor = (int*)(ws + off);   off += (size_t)NN * 4;
    float* recip  = (float*)(ws + off); off += (size_t)NN * 4;
    int*   scol   = (int*)(ws + off);   off += (size_t)NE * 4;
    unsigned short* Wp1p = (unsigned short*)(ws + off); off += packBytes;
    unsigned short* pk[8];   // W1l,W1r,W2l,W2r x {hi,lo}
    for (int i = 0; i < 8; ++i) { pk[i] = (unsigned short*)(ws + off); off += packBytes; }

    const int MB = (NN + 63) / 64;   // 313 M-blocks of 64 rows

    // Build CSR + pack weights
    hipMemsetAsync(deg, 0, NN * 4, stream);
    k_deg<<<(NE + 255) / 256, 256, 0, stream>>>(adj_row, deg);
    k_scan<<<1, 256, 0, stream>>>(deg, offs, cursor, recip);
    k_fill<<<(NE + 255) / 256, 256, 0, stream>>>(adj_row, adj_col, cursor, scol);
    k_pack<<<32, 256, 0, stream>>>(Wp1, Wp1p);
    k_packs<<<128, 256, 0, stream>>>(W1l, W1r, W2l, W2r,
                                     pk[0], pk[2], pk[4], pk[6],
                                     pk[1], pk[3], pk[5], pk[7]);

    // Layer 1 (out = x1, never aliases -> N-split always safe)
    k_agg<<<(NN + 3) / 4, 256, 0, stream>>>(offs, scol, recip, emb, agg);
    k_sagem<1, 1><<<MB * 2, 256, 0, stream>>>(agg, emb,
                                              pk[0], pk[1], pk[2], pk[3], b1, x1);

    // Layer 2
    k_agg<<<(NN + 3) / 4, 256, 0, stream>>>(offs, scol, recip, x1, agg);
    if (big) {
        k_sagem<0, 1><<<MB * 2, 256, 0, stream>>>(agg, x1,
                                                  pk[4], pk[5], pk[6], pk[7], b2, x2);
    } else {
        // x2 aliases agg: full-N blocks touch only their own rows -> safe
        k_sagem<0, 0><<<MB, 256, 0, stream>>>(agg, x1,
                                              pk[4], pk[5], pk[6], pk[7], b2, x2);
    }

    // Predictor (bf16 MFMA)
    k_pred<<<(NQ + 63) / 64, 256, 0, stream>>>(edges, x2, Wp1p, bp1, Wp2, bp2, out);
}

// Round 6
// 384.646 us; speedup vs baseline: 1.3053x; 1.0287x over previous
//
#include <hip/hip_runtime.h>
#include <cstddef>

// Problem constants (match reference)
constexpr int NN = 20000;    // nodes
constexpr int NE = 320000;   // edges
constexpr int NQ = 100000;   // queries
constexpr int DD = 256;      // feature dim

typedef __attribute__((ext_vector_type(8))) short bf16x8;
typedef __attribute__((ext_vector_type(4))) float f32x4;
typedef __attribute__((ext_vector_type(4))) unsigned short u16x4;

__device__ inline unsigned short f2bf(float f) {
    union { float f; unsigned u; } v; v.f = f;
    unsigned r = v.u + 0x7fffu + ((v.u >> 16) & 1u);   // RNE
    return (unsigned short)(r >> 16);
}
__device__ inline float bf2f(unsigned short h) {
    union { unsigned u; float f; } t; t.u = ((unsigned)h) << 16;
    return t.f;
}

// ---------------------------------------------------------------------------
// Degree histogram (int): deg[row[e]] += 1
__global__ __launch_bounds__(256) void k_deg(const int* __restrict__ row,
                                             int* __restrict__ deg) {
    int e = blockIdx.x * 256 + threadIdx.x;
    if (e < NE) atomicAdd(&deg[row[e]], 1);
}

// Single-block exclusive scan over deg -> offs[NN+1], cursor copy, recip.
__global__ __launch_bounds__(256) void k_scan(const int* __restrict__ deg,
                                              int* __restrict__ offs,
                                              int* __restrict__ cursor,
                                              float* __restrict__ recip) {
    __shared__ int wsum[4];
    __shared__ int s_carry;
    const int tid = threadIdx.x;
    const int wid = tid >> 6;
    const int lane = tid & 63;
    if (tid == 0) s_carry = 0;
    __syncthreads();
    for (int base = 0; base < NN; base += 256) {
        int i = base + tid;
        int v = (i < NN) ? deg[i] : 0;
        int sc = v;
#pragma unroll
        for (int d = 1; d < 64; d <<= 1) {
            int t = __shfl_up(sc, d);
            if (lane >= d) sc += t;
        }
        if (lane == 63) wsum[wid] = sc;
        __syncthreads();
        int wpre = 0;
        for (int w = 0; w < wid; ++w) wpre += wsum[w];
        int carry = s_carry;
        int incl = carry + wpre + sc;
        if (i < NN) {
            offs[i] = incl - v;
            cursor[i] = incl - v;
            recip[i] = 1.0f / fmaxf((float)v, 1.0f);
        }
        __syncthreads();
        if (tid == 255) s_carry = incl;
        __syncthreads();
    }
    if (tid == 0) offs[NN] = s_carry;
}

// Fill CSR adjacency: scol[cursor[row[e]]++] = col[e]
__global__ __launch_bounds__(256) void k_fill(const int* __restrict__ row,
                                              const int* __restrict__ col,
                                              int* __restrict__ cursor,
                                              int* __restrict__ scol) {
    int e = blockIdx.x * 256 + threadIdx.x;
    if (e < NE) {
        int r = row[e];
        int p = atomicAdd(&cursor[r], 1);
        scol[p] = col[e];
    }
}

// ---------------------------------------------------------------------------
// Gather-aggregate (mean), f32 source: agg[i,:] = recip[i]*sum x[c,:]
__global__ __launch_bounds__(256) void k_agg_f(const int* __restrict__ offs,
                                               const int* __restrict__ scol,
                                               const float* __restrict__ recip,
                                               const float* __restrict__ x,
                                               float* __restrict__ agg) {
    int node = blockIdx.x * 4 + (threadIdx.x >> 6);
    int lane = threadIdx.x & 63;
    if (node >= NN) return;
    int s = offs[node];
    int e = offs[node + 1];
    float4 a0 = {0,0,0,0}, a1 = {0,0,0,0}, a2 = {0,0,0,0}, a3 = {0,0,0,0};
    int p = s;
    for (; p + 3 < e; p += 4) {
        int c0 = scol[p], c1 = scol[p+1], c2 = scol[p+2], c3 = scol[p+3];
        float4 v0 = *reinterpret_cast<const float4*>(x + (size_t)c0 * DD + lane * 4);
        float4 v1 = *reinterpret_cast<const float4*>(x + (size_t)c1 * DD + lane * 4);
        float4 v2 = *reinterpret_cast<const float4*>(x + (size_t)c2 * DD + lane * 4);
        float4 v3 = *reinterpret_cast<const float4*>(x + (size_t)c3 * DD + lane * 4);
        a0.x += v0.x; a0.y += v0.y; a0.z += v0.z; a0.w += v0.w;
        a1.x += v1.x; a1.y += v1.y; a1.z += v1.z; a1.w += v1.w;
        a2.x += v2.x; a2.y += v2.y; a2.z += v2.z; a2.w += v2.w;
        a3.x += v3.x; a3.y += v3.y; a3.z += v3.z; a3.w += v3.w;
    }
    for (; p < e; ++p) {
        int c0 = scol[p];
        float4 v0 = *reinterpret_cast<const float4*>(x + (size_t)c0 * DD + lane * 4);
        a0.x += v0.x; a0.y += v0.y; a0.z += v0.z; a0.w += v0.w;
    }
    float rc = recip[node];
    float4 o;
    o.x = (a0.x + a1.x + a2.x + a3.x) * rc;
    o.y = (a0.y + a1.y + a2.y + a3.y) * rc;
    o.z = (a0.z + a1.z + a2.z + a3.z) * rc;
    o.w = (a0.w + a1.w + a2.w + a3.w) * rc;
    *reinterpret_cast<float4*>(agg + (size_t)node * DD + lane * 4) = o;
}

// Gather-aggregate, bf16 source (512B rows), f32 accumulate/output.
__global__ __launch_bounds__(256) void k_agg_h(const int* __restrict__ offs,
                                               const int* __restrict__ scol,
                                               const float* __restrict__ recip,
                                               const unsigned short* __restrict__ x,
                                               float* __restrict__ agg) {
    int node = blockIdx.x * 4 + (threadIdx.x >> 6);
    int lane = threadIdx.x & 63;
    if (node >= NN) return;
    int s = offs[node];
    int e = offs[node + 1];
    float a0[4] = {0,0,0,0}, a1[4] = {0,0,0,0}, a2[4] = {0,0,0,0}, a3[4] = {0,0,0,0};
    int p = s;
    for (; p + 3 < e; p += 4) {
        int c0 = scol[p], c1 = scol[p+1], c2 = scol[p+2], c3 = scol[p+3];
        u16x4 v0 = *reinterpret_cast<const u16x4*>(x + (size_t)c0 * DD + lane * 4);
        u16x4 v1 = *reinterpret_cast<const u16x4*>(x + (size_t)c1 * DD + lane * 4);
        u16x4 v2 = *reinterpret_cast<const u16x4*>(x + (size_t)c2 * DD + lane * 4);
        u16x4 v3 = *reinterpret_cast<const u16x4*>(x + (size_t)c3 * DD + lane * 4);
#pragma unroll
        for (int i = 0; i < 4; ++i) {
            a0[i] += bf2f(v0[i]); a1[i] += bf2f(v1[i]);
            a2[i] += bf2f(v2[i]); a3[i] += bf2f(v3[i]);
        }
    }
    for (; p < e; ++p) {
        int c0 = scol[p];
        u16x4 v0 = *reinterpret_cast<const u16x4*>(x + (size_t)c0 * DD + lane * 4);
#pragma unroll
        for (int i = 0; i < 4; ++i) a0[i] += bf2f(v0[i]);
    }
    float rc = recip[node];
    float4 o;
    o.x = (a0[0] + a1[0] + a2[0] + a3[0]) * rc;
    o.y = (a0[1] + a1[1] + a2[1] + a3[1]) * rc;
    o.z = (a0[2] + a1[2] + a2[2] + a3[2]) * rc;
    o.w = (a0[3] + a1[3] + a2[3] + a3[3]) * rc;
    *reinterpret_cast<float4*>(agg + (size_t)node * DD + lane * 4) = o;
}

// ---------------------------------------------------------------------------
// Pack one 256x256 f32 matrix into bf16 MFMA B-fragment layout, hi + lo split.
__global__ __launch_bounds__(256) void k_packs(
    const float* __restrict__ w0, const float* __restrict__ w1,
    const float* __restrict__ w2, const float* __restrict__ w3,
    unsigned short* __restrict__ h0, unsigned short* __restrict__ h1,
    unsigned short* __restrict__ h2, unsigned short* __restrict__ h3,
    unsigned short* __restrict__ l0, unsigned short* __restrict__ l1,
    unsigned short* __restrict__ l2, unsigned short* __restrict__ l3) {
    int m = blockIdx.x >> 5;
    int idx = (blockIdx.x & 31) * 256 + threadIdx.x;   // 0..8191
    const float* W = (m == 0) ? w0 : (m == 1) ? w1 : (m == 2) ? w2 : w3;
    unsigned short* H = (m == 0) ? h0 : (m == 1) ? h1 : (m == 2) ? h2 : h3;
    unsigned short* L = (m == 0) ? l0 : (m == 1) ? l1 : (m == 2) ? l2 : l3;
    int t = idx >> 6, lane = idx & 63;
    int kt = t >> 4, nt = t & 15;
    int k0 = kt * 32 + (lane >> 4) * 8;
    int n = nt * 16 + (lane & 15);
    unsigned uh[4], ul[4];
#pragma unroll
    for (int i = 0; i < 4; ++i) {
        float fa = W[(size_t)(k0 + 2 * i) * DD + n];
        float fb = W[(size_t)(k0 + 2 * i + 1) * DD + n];
        unsigned short ha = f2bf(fa), hb = f2bf(fb);
        unsigned short la = f2bf(fa - bf2f(ha)), lb = f2bf(fb - bf2f(hb));
        uh[i] = (unsigned)ha | ((unsigned)hb << 16);
        ul[i] = (unsigned)la | ((unsigned)lb << 16);
    }
    *reinterpret_cast<uint4*>(H + (size_t)idx * 8) = make_uint4(uh[0], uh[1], uh[2], uh[3]);
    *reinterpret_cast<uint4*>(L + (size_t)idx * 8) = make_uint4(ul[0], ul[1], ul[2], ul[3]);
}

// Pack Wp1 (hi only) for the predictor.
__global__ __launch_bounds__(256) void k_pack(const float* __restrict__ W,
                                              unsigned short* __restrict__ P) {
    int idx = blockIdx.x * 256 + threadIdx.x;
    if (idx >= 128 * 64) return;
    int t = idx >> 6, lane = idx & 63;
    int kt = t >> 4, nt = t & 15;
    int k0 = kt * 32 + (lane >> 4) * 8;
    int n = nt * 16 + (lane & 15);
    unsigned w[4];
#pragma unroll
    for (int i = 0; i < 4; ++i) {
        unsigned lo = f2bf(W[(size_t)(k0 + 2 * i) * DD + n]);
        unsigned hi = f2bf(W[(size_t)(k0 + 2 * i + 1) * DD + n]);
        w[i] = lo | (hi << 16);
    }
    *reinterpret_cast<uint4*>(P + (size_t)idx * 8) = make_uint4(w[0], w[1], w[2], w[3]);
}

// ---------------------------------------------------------------------------
// Split-bf16 A-fragment conversion: 8 consecutive f32 -> hi/lo bf16x8
__device__ inline void cvt8(const float* __restrict__ p, bf16x8& h, bf16x8& l) {
    float4 f0 = *reinterpret_cast<const float4*>(p);
    float4 f1 = *reinterpret_cast<const float4*>(p + 4);
    float fv[8] = {f0.x, f0.y, f0.z, f0.w, f1.x, f1.y, f1.z, f1.w};
#pragma unroll
    for (int i = 0; i < 8; ++i) {
        unsigned short hb = f2bf(fv[i]);
        h[i] = (short)hb;
        l[i] = (short)f2bf(fv[i] - bf2f(hb));
    }
}

// ---------------------------------------------------------------------------
// MFMA SAGE layer: out_bf16 = [relu]( A0 @ Wl + b + A1 @ Wr ).
// A0 = agg (f32, split-bf16 3-term). A1: f32 (3-term) if A1F32 else bf16 (2-term).
// Wave = one 16-row M-tile x 128 cols (N-split). Block = 4 waves = 64 rows.
// blockIdx = mblk*2 + nhalf. out is a distinct buffer (no aliasing).
template <int RELU, int A1F32>
__global__ __launch_bounds__(256) void k_sagem(
    const float* __restrict__ A0,
    const float* __restrict__ A1f, const unsigned short* __restrict__ A1h,
    const unsigned short* __restrict__ Wlh, const unsigned short* __restrict__ Wll,
    const unsigned short* __restrict__ Wrh, const unsigned short* __restrict__ Wrl,
    const float* __restrict__ b, unsigned short* __restrict__ out) {
    const int nh   = blockIdx.x & 1;
    const int mblk = blockIdx.x >> 1;
    const int wave = threadIdx.x >> 6;
    const int lane = threadIdx.x & 63;
    const int row0 = mblk * 64 + wave * 16;
    const int kcol = (lane >> 4) * 8;
    const int ar = min(row0 + (lane & 15), NN - 1);

    f32x4 acc[8];
#pragma unroll
    for (int nt = 0; nt < 8; ++nt) acc[nt] = {0, 0, 0, 0};

#pragma unroll 2
    for (int kt = 0; kt < 8; ++kt) {
        bf16x8 a0h, a0l, a1h, a1l;
        cvt8(A0 + (size_t)ar * DD + kt * 32 + kcol, a0h, a0l);
        if (A1F32) {
            cvt8(A1f + (size_t)ar * DD + kt * 32 + kcol, a1h, a1l);
        } else {
            a1h = *reinterpret_cast<const bf16x8*>(A1h + (size_t)ar * DD + kt * 32 + kcol);
        }
#pragma unroll
        for (int nt = 0; nt < 8; ++nt) {
            const size_t fo = ((size_t)((kt * 16 + nh * 8 + nt) * 64 + lane)) * 8;
            bf16x8 blh = *reinterpret_cast<const bf16x8*>(Wlh + fo);
            bf16x8 bll = *reinterpret_cast<const bf16x8*>(Wll + fo);
            bf16x8 brh = *reinterpret_cast<const bf16x8*>(Wrh + fo);
            bf16x8 brl = *reinterpret_cast<const bf16x8*>(Wrl + fo);
            acc[nt] = __builtin_amdgcn_mfma_f32_16x16x32_bf16(a0h, blh, acc[nt], 0, 0, 0);
            acc[nt] = __builtin_amdgcn_mfma_f32_16x16x32_bf16(a0l, blh, acc[nt], 0, 0, 0);
            acc[nt] = __builtin_amdgcn_mfma_f32_16x16x32_bf16(a0h, bll, acc[nt], 0, 0, 0);
            acc[nt] = __builtin_amdgcn_mfma_f32_16x16x32_bf16(a1h, brh, acc[nt], 0, 0, 0);
            if (A1F32)
                acc[nt] = __builtin_amdgcn_mfma_f32_16x16x32_bf16(a1l, brh, acc[nt], 0, 0, 0);
            acc[nt] = __builtin_amdgcn_mfma_f32_16x16x32_bf16(a1h, brl, acc[nt], 0, 0, 0);
        }
    }

    // Epilogue: bias (+relu) + bf16 store. acc[nt][j]: row=(lane>>4)*4+j, col=lane&15.
    const int n0 = lane & 15;
    const int rg = (lane >> 4) * 4;
#pragma unroll
    for (int nt = 0; nt < 8; ++nt) {
        int n = (nh * 8 + nt) * 16 + n0;
        float bias = b[n];
#pragma unroll
        for (int j = 0; j < 4; ++j) {
            int r = row0 + rg + j;
            if (r < NN) {
                float v = acc[nt][j] + bias;
                if (RELU) v = fmaxf(v, 0.0f);
                out[(size_t)r * DD + n] = f2bf(v);
            }
        }
    }
}

// ---------------------------------------------------------------------------
// Predictor: h = x2[a]*x2[b] (bf16) -> MFMA GEMM (cooperative N-split across
// waves) -> bias/relu/Wp2-dot/sigmoid. Block = 64 queries, 4 waves.
// Wave w computes cols w*64..w*64+63 for ALL 64 rows; B-traffic /4.
__global__ __launch_bounds__(256) void k_pred(const int* __restrict__ edges,
                                              const unsigned short* __restrict__ x2,
                                              const unsigned short* __restrict__ Wp1p,
                                              const float* __restrict__ bp1,
                                              const float* __restrict__ Wp2,
                                              const float* __restrict__ bp2,
                                              float* __restrict__ out) {
    __shared__ unsigned short sh[64][264];   // bf16 h tile, padded stride
    __shared__ float psum[4][64];
    const int tid = threadIdx.x;
    const int wave = tid >> 6;
    const int lane = tid & 63;
    const int q0 = blockIdx.x * 64;
    const bool full = (q0 + 64 <= NQ);

    // Gather phase: wave w fills rows w*16..w*16+15 (512B bf16 rows).
    for (int s = 0; s < 16; ++s) {
        int r = wave * 16 + s;
        int q = q0 + r;
        u16x4 pk = {0, 0, 0, 0};
        if (full || q < NQ) {
            int a = edges[q];
            int c = edges[NQ + q];
            u16x4 ua = *reinterpret_cast<const u16x4*>(x2 + (size_t)a * DD + lane * 4);
            u16x4 uc = *reinterpret_cast<const u16x4*>(x2 + (size_t)c * DD + lane * 4);
#pragma unroll
            for (int i = 0; i < 4; ++i) pk[i] = f2bf(bf2f(ua[i]) * bf2f(uc[i]));
        }
        *reinterpret_cast<u16x4*>(&sh[r][lane * 4]) = pk;
    }
    __syncthreads();

    // GEMM: wave handles nt = wave*4..wave*4+3 for all 4 row-tiles.
    f32x4 acc[4][4];   // [mtile][ntl]
#pragma unroll
    for (int m = 0; m < 4; ++m)
#pragma unroll
        for (int n = 0; n < 4; ++n) acc[m][n] = {0, 0, 0, 0};

    const int akoff = (lane >> 4) * 8;
    const int arl = lane & 15;
    for (int kt = 0; kt < 8; ++kt) {
        bf16x8 af[4];
#pragma unroll
        for (int m = 0; m < 4; ++m)
            af[m] = *reinterpret_cast<const bf16x8*>(&sh[m * 16 + arl][kt * 32 + akoff]);
#pragma unroll
        for (int ntl = 0; ntl < 4; ++ntl) {
            int nt = wave * 4 + ntl;
            bf16x8 bfrag = *reinterpret_cast<const bf16x8*>(
                Wp1p + ((size_t)((kt * 16 + nt) * 64 + lane)) * 8);
#pragma unroll
            for (int m = 0; m < 4; ++m)
                acc[m][ntl] = __builtin_amdgcn_mfma_f32_16x16x32_bf16(af[m], bfrag, acc[m][ntl], 0, 0, 0);
        }
    }

    // Epilogue: bias+relu+Wp2 partial dot within wave's 64 cols.
    // acc[m][ntl][j]: row = m*16+(lane>>4)*4+j, col = (wave*4+ntl)*16+(lane&15).
    float rs[4][4];   // [m][j]
#pragma unroll
    for (int m = 0; m < 4; ++m)
#pragma unroll
        for (int j = 0; j < 4; ++j) rs[m][j] = 0.0f;
#pragma unroll
    for (int ntl = 0; ntl < 4; ++ntl) {
        int n = (wave * 4 + ntl) * 16 + (lane & 15);
        float bias = bp1[n];
        float w2 = Wp2[n];
#pragma unroll
        for (int m = 0; m < 4; ++m)
#pragma unroll
            for (int j = 0; j < 4; ++j)
                rs[m][j] += fmaxf(acc[m][ntl][j] + bias, 0.0f) * w2;
    }
    // Reduce across the 16 col-lanes (lane&15).
#pragma unroll
    for (int msk = 1; msk < 16; msk <<= 1) {
#pragma unroll
        for (int m = 0; m < 4; ++m)
#pragma unroll
            for (int j = 0; j < 4; ++j) rs[m][j] += __shfl_xor(rs[m][j], msk);
    }
    if ((lane & 15) == 0) {
        int rg = (lane >> 4) * 4;
#pragma unroll
        for (int m = 0; m < 4; ++m)
#pragma unroll
            for (int j = 0; j < 4; ++j)
                psum[wave][m * 16 + rg + j] = rs[m][j];
    }
    __syncthreads();

    if (tid < 64) {
        int q = q0 + tid;
        if (q < NQ) {
            float z = psum[0][tid] + psum[1][tid] + psum[2][tid] + psum[3][tid] + bp2[0];
            out[q] = 1.0f / (1.0f + expf(-z));
        }
    }
}

// ---------------------------------------------------------------------------
extern "C" void kernel_launch(void* const* d_in, const int* in_sizes, int n_in,
                              void* d_out, int out_size, void* d_ws, size_t ws_size,
                              hipStream_t stream) {
    const int*   adj_row = (const int*)d_in[0];
    const int*   adj_col = (const int*)d_in[1];
    const int*   edges   = (const int*)d_in[2];
    const float* emb     = (const float*)d_in[3];
    const float* W1l     = (const float*)d_in[4];
    const float* b1      = (const float*)d_in[5];
    const float* W1r     = (const float*)d_in[6];
    const float* W2l     = (const float*)d_in[7];
    const float* b2      = (const float*)d_in[8];
    const float* W2r     = (const float*)d_in[9];
    const float* Wp1     = (const float*)d_in[10];
    const float* bp1     = (const float*)d_in[11];
    const float* Wp2     = (const float*)d_in[12];
    const float* bp2     = (const float*)d_in[13];
    float* out = (float*)d_out;

    const size_t featF = (size_t)NN * DD * 4;   // 20.48 MB
    const size_t featH = (size_t)NN * DD * 2;   // 10.24 MB
    const size_t packBytes = (size_t)DD * DD * 2;

    char* ws = (char*)d_ws;
    size_t off = 0;
    float*          agg = (float*)(ws + off);          off += featF;
    unsigned short* x1  = (unsigned short*)(ws + off); off += featH;
    unsigned short* x2  = (unsigned short*)(ws + off); off += featH;
    int*   deg    = (int*)(ws + off);   off += (size_t)NN * 4;
    int*   offs   = (int*)(ws + off);   off += (size_t)(NN + 1) * 4;
    int*   cursor = (int*)(ws + off);   off += (size_t)NN * 4;
    float* recip  = (float*)(ws + off); off += (size_t)NN * 4;
    int*   scol   = (int*)(ws + off);   off += (size_t)NE * 4;
    unsigned short* Wp1p = (unsigned short*)(ws + off); off += packBytes;
    unsigned short* pk[8];   // W1l,W1r,W2l,W2r x {hi,lo}
    for (int i = 0; i < 8; ++i) { pk[i] = (unsigned short*)(ws + off); off += packBytes; }

    const int MB = (NN + 63) / 64;   // 313 M-blocks of 64 rows

    // Build CSR + pack weights
    hipMemsetAsync(deg, 0, NN * 4, stream);
    k_deg<<<(NE + 255) / 256, 256, 0, stream>>>(adj_row, deg);
    k_scan<<<1, 256, 0, stream>>>(deg, offs, cursor, recip);
    k_fill<<<(NE + 255) / 256, 256, 0, stream>>>(adj_row, adj_col, cursor, scol);
    k_pack<<<32, 256, 0, stream>>>(Wp1, Wp1p);
    k_packs<<<128, 256, 0, stream>>>(W1l, W1r, W2l, W2r,
                                     pk[0], pk[2], pk[4], pk[6],
                                     pk[1], pk[3], pk[5], pk[7]);

    // Layer 1: agg from f32 emb; A1 = emb (f32, 3-term); out x1 bf16.
    k_agg_f<<<(NN + 3) / 4, 256, 0, stream>>>(offs, scol, recip, emb, agg);
    k_sagem<1, 1><<<MB * 2, 256, 0, stream>>>(agg, emb, nullptr,
                                              pk[0], pk[1], pk[2], pk[3], b1, x1);

    // Layer 2: agg from bf16 x1; A1 = x1 (bf16, 2-term); out x2 bf16.
    k_agg_h<<<(NN + 3) / 4, 256, 0, stream>>>(offs, scol, recip, x1, agg);
    k_sagem<0, 0><<<MB * 2, 256, 0, stream>>>(agg, nullptr, x1,
                                              pk[4], pk[5], pk[6], pk[7], b2, x2);

    // Predictor (cooperative bf16 MFMA)
    k_pred<<<(NQ + 63) / 64, 256, 0, stream>>>(edges, x2, Wp1p, bp1, Wp2, bp2, out);
}

// Round 7
// 333.904 us; speedup vs baseline: 1.5036x; 1.1520x over previous
//
#include <hip/hip_runtime.h>
#include <cstddef>

// Problem constants (match reference)
constexpr int NN = 20000;    // nodes
constexpr int NE = 320000;   // edges
constexpr int NQ = 100000;   // queries
constexpr int DD = 256;      // feature dim
constexpr int NB = (NN + 255) / 256;   // scan blocks (79)

typedef __attribute__((ext_vector_type(8))) short bf16x8;
typedef __attribute__((ext_vector_type(4))) float f32x4;
typedef __attribute__((ext_vector_type(4))) unsigned short u16x4;
typedef __attribute__((ext_vector_type(8))) unsigned short u16x8;

__device__ inline unsigned short f2bf(float f) {
    union { float f; unsigned u; } v; v.f = f;
    unsigned r = v.u + 0x7fffu + ((v.u >> 16) & 1u);   // RNE
    return (unsigned short)(r >> 16);
}
__device__ inline float bf2f(unsigned short h) {
    union { unsigned u; float f; } t; t.u = ((unsigned)h) << 16;
    return t.f;
}

// ---------------------------------------------------------------------------
// Cast emb f32 -> bf16 (16B/thread)
__global__ __launch_bounds__(256) void k_cast(const float* __restrict__ x,
                                              unsigned short* __restrict__ y) {
    int i = blockIdx.x * 256 + threadIdx.x;   // 8 elems per thread
    if (i >= NN * DD / 8) return;
    float4 f0 = *reinterpret_cast<const float4*>(x + (size_t)i * 8);
    float4 f1 = *reinterpret_cast<const float4*>(x + (size_t)i * 8 + 4);
    u16x8 o;
    o[0] = f2bf(f0.x); o[1] = f2bf(f0.y); o[2] = f2bf(f0.z); o[3] = f2bf(f0.w);
    o[4] = f2bf(f1.x); o[5] = f2bf(f1.y); o[6] = f2bf(f1.z); o[7] = f2bf(f1.w);
    *reinterpret_cast<u16x8*>(y + (size_t)i * 8) = o;
}

// ---------------------------------------------------------------------------
// Degree histogram (int): deg[row[e]] += 1
__global__ __launch_bounds__(256) void k_deg(const int* __restrict__ row,
                                             int* __restrict__ deg) {
    int e = blockIdx.x * 256 + threadIdx.x;
    if (e < NE) atomicAdd(&deg[row[e]], 1);
}

// Parallel scan, step 1: block-local exclusive scan + block sums.
__global__ __launch_bounds__(256) void k_scan1(const int* __restrict__ deg,
                                               int* __restrict__ offs,
                                               int* __restrict__ bsum) {
    __shared__ int wsum[4];
    const int tid = threadIdx.x, lane = tid & 63, wid = tid >> 6;
    int i = blockIdx.x * 256 + tid;
    int v = (i < NN) ? deg[i] : 0;
    int sc = v;
#pragma unroll
    for (int d = 1; d < 64; d <<= 1) {
        int t = __shfl_up(sc, d);
        if (lane >= d) sc += t;
    }
    if (lane == 63) wsum[wid] = sc;
    __syncthreads();
    int wpre = 0;
    for (int w = 0; w < wid; ++w) wpre += wsum[w];
    if (i < NN) offs[i] = wpre + sc - v;
    if (tid == 255) bsum[blockIdx.x] = wpre + sc;
}

// Step 2: exclusive scan over the NB block sums (single small block).
__global__ __launch_bounds__(256) void k_scan2(int* __restrict__ bsum) {
    __shared__ int wsum[4];
    const int tid = threadIdx.x, lane = tid & 63, wid = tid >> 6;
    int v = (tid < NB) ? bsum[tid] : 0;
    int sc = v;
#pragma unroll
    for (int d = 1; d < 64; d <<= 1) {
        int t = __shfl_up(sc, d);
        if (lane >= d) sc += t;
    }
    if (lane == 63) wsum[wid] = sc;
    __syncthreads();
    int wpre = 0;
    for (int w = 0; w < wid; ++w) wpre += wsum[w];
    if (tid < NB) bsum[tid] = wpre + sc - v;
}

// Step 3: add block prefix; emit cursor + recip; offs[NN] = NE.
__global__ __launch_bounds__(256) void k_scan3(const int* __restrict__ deg,
                                               const int* __restrict__ bsum,
                                               int* __restrict__ offs,
                                               int* __restrict__ cursor,
                                               float* __restrict__ recip) {
    int i = blockIdx.x * 256 + threadIdx.x;
    if (i < NN) {
        int o = offs[i] + bsum[i >> 8];
        offs[i] = o;
        cursor[i] = o;
        recip[i] = 1.0f / fmaxf((float)deg[i], 1.0f);
    }
    if (i == 0) offs[NN] = NE;
}

// Fill CSR adjacency: scol[cursor[row[e]]++] = col[e]
__global__ __launch_bounds__(256) void k_fill(const int* __restrict__ row,
                                              const int* __restrict__ col,
                                              int* __restrict__ cursor,
                                              int* __restrict__ scol) {
    int e = blockIdx.x * 256 + threadIdx.x;
    if (e < NE) {
        int r = row[e];
        int p = atomicAdd(&cursor[r], 1);
        scol[p] = col[e];
    }
}

// ---------------------------------------------------------------------------
// Gather-aggregate, bf16 source (512B rows), f32 accumulate/output.
__global__ __launch_bounds__(256) void k_agg_h(const int* __restrict__ offs,
                                               const int* __restrict__ scol,
                                               const float* __restrict__ recip,
                                               const unsigned short* __restrict__ x,
                                               float* __restrict__ agg) {
    int node = blockIdx.x * 4 + (threadIdx.x >> 6);
    int lane = threadIdx.x & 63;
    if (node >= NN) return;
    int s = offs[node];
    int e = offs[node + 1];
    float a0[4] = {0,0,0,0}, a1[4] = {0,0,0,0}, a2[4] = {0,0,0,0}, a3[4] = {0,0,0,0};
    int p = s;
    for (; p + 3 < e; p += 4) {
        int c0 = scol[p], c1 = scol[p+1], c2 = scol[p+2], c3 = scol[p+3];
        u16x4 v0 = *reinterpret_cast<const u16x4*>(x + (size_t)c0 * DD + lane * 4);
        u16x4 v1 = *reinterpret_cast<const u16x4*>(x + (size_t)c1 * DD + lane * 4);
        u16x4 v2 = *reinterpret_cast<const u16x4*>(x + (size_t)c2 * DD + lane * 4);
        u16x4 v3 = *reinterpret_cast<const u16x4*>(x + (size_t)c3 * DD + lane * 4);
#pragma unroll
        for (int i = 0; i < 4; ++i) {
            a0[i] += bf2f(v0[i]); a1[i] += bf2f(v1[i]);
            a2[i] += bf2f(v2[i]); a3[i] += bf2f(v3[i]);
        }
    }
    for (; p < e; ++p) {
        int c0 = scol[p];
        u16x4 v0 = *reinterpret_cast<const u16x4*>(x + (size_t)c0 * DD + lane * 4);
#pragma unroll
        for (int i = 0; i < 4; ++i) a0[i] += bf2f(v0[i]);
    }
    float rc = recip[node];
    float4 o;
    o.x = (a0[0] + a1[0] + a2[0] + a3[0]) * rc;
    o.y = (a0[1] + a1[1] + a2[1] + a3[1]) * rc;
    o.z = (a0[2] + a1[2] + a2[2] + a3[2]) * rc;
    o.w = (a0[3] + a1[3] + a2[3] + a3[3]) * rc;
    *reinterpret_cast<float4*>(agg + (size_t)node * DD + lane * 4) = o;
}

// ---------------------------------------------------------------------------
// Pack 5 f32 256x256 matrices into bf16 MFMA B-fragment layout.
// m = 0..3: hi + lo split (W1l,W1r,W2l,W2r). m = 4: hi only (Wp1).
__global__ __launch_bounds__(256) void k_packs(
    const float* __restrict__ w0, const float* __restrict__ w1,
    const float* __restrict__ w2, const float* __restrict__ w3,
    const float* __restrict__ w4,
    unsigned short* __restrict__ h0, unsigned short* __restrict__ h1,
    unsigned short* __restrict__ h2, unsigned short* __restrict__ h3,
    unsigned short* __restrict__ h4,
    unsigned short* __restrict__ l0, unsigned short* __restrict__ l1,
    unsigned short* __restrict__ l2, unsigned short* __restrict__ l3) {
    int m = blockIdx.x >> 5;
    int idx = (blockIdx.x & 31) * 256 + threadIdx.x;   // 0..8191
    const float* W = (m == 0) ? w0 : (m == 1) ? w1 : (m == 2) ? w2 : (m == 3) ? w3 : w4;
    unsigned short* H = (m == 0) ? h0 : (m == 1) ? h1 : (m == 2) ? h2 : (m == 3) ? h3 : h4;
    unsigned short* L = (m == 0) ? l0 : (m == 1) ? l1 : (m == 2) ? l2 : (m == 3) ? l3 : nullptr;
    int t = idx >> 6, lane = idx & 63;
    int kt = t >> 4, nt = t & 15;
    int k0 = kt * 32 + (lane >> 4) * 8;
    int n = nt * 16 + (lane & 15);
    unsigned uh[4], ul[4];
#pragma unroll
    for (int i = 0; i < 4; ++i) {
        float fa = W[(size_t)(k0 + 2 * i) * DD + n];
        float fb = W[(size_t)(k0 + 2 * i + 1) * DD + n];
        unsigned short ha = f2bf(fa), hb = f2bf(fb);
        unsigned short la = f2bf(fa - bf2f(ha)), lb = f2bf(fb - bf2f(hb));
        uh[i] = (unsigned)ha | ((unsigned)hb << 16);
        ul[i] = (unsigned)la | ((unsigned)lb << 16);
    }
    *reinterpret_cast<uint4*>(H + (size_t)idx * 8) = make_uint4(uh[0], uh[1], uh[2], uh[3]);
    if (L)
        *reinterpret_cast<uint4*>(L + (size_t)idx * 8) = make_uint4(ul[0], ul[1], ul[2], ul[3]);
}

// ---------------------------------------------------------------------------
// Split-bf16 A-fragment conversion: 8 consecutive f32 -> hi/lo bf16x8
__device__ inline void cvt8(const float* __restrict__ p, bf16x8& h, bf16x8& l) {
    float4 f0 = *reinterpret_cast<const float4*>(p);
    float4 f1 = *reinterpret_cast<const float4*>(p + 4);
    float fv[8] = {f0.x, f0.y, f0.z, f0.w, f1.x, f1.y, f1.z, f1.w};
#pragma unroll
    for (int i = 0; i < 8; ++i) {
        unsigned short hb = f2bf(fv[i]);
        h[i] = (short)hb;
        l[i] = (short)f2bf(fv[i] - bf2f(hb));
    }
}

// ---------------------------------------------------------------------------
// MFMA SAGE layer: out_bf16 = [relu]( A0 @ Wl + b + A1 @ Wr ).
// A0 = agg (f32, split-bf16 3-term). A1 = bf16 (2-term, A exact in bf16).
// Wave = one 16-row M-tile x 128 cols (N-split). Block = 4 waves = 64 rows.
template <int RELU>
__global__ __launch_bounds__(256) void k_sagem(
    const float* __restrict__ A0, const unsigned short* __restrict__ A1h,
    const unsigned short* __restrict__ Wlh, const unsigned short* __restrict__ Wll,
    const unsigned short* __restrict__ Wrh, const unsigned short* __restrict__ Wrl,
    const float* __restrict__ b, unsigned short* __restrict__ out) {
    const int nh   = blockIdx.x & 1;
    const int mblk = blockIdx.x >> 1;
    const int wave = threadIdx.x >> 6;
    const int lane = threadIdx.x & 63;
    const int row0 = mblk * 64 + wave * 16;
    const int kcol = (lane >> 4) * 8;
    const int ar = min(row0 + (lane & 15), NN - 1);

    f32x4 acc[8];
#pragma unroll
    for (int nt = 0; nt < 8; ++nt) acc[nt] = {0, 0, 0, 0};

#pragma unroll 2
    for (int kt = 0; kt < 8; ++kt) {
        bf16x8 a0h, a0l;
        cvt8(A0 + (size_t)ar * DD + kt * 32 + kcol, a0h, a0l);
        bf16x8 a1 = *reinterpret_cast<const bf16x8*>(A1h + (size_t)ar * DD + kt * 32 + kcol);
#pragma unroll
        for (int nt = 0; nt < 8; ++nt) {
            const size_t fo = ((size_t)((kt * 16 + nh * 8 + nt) * 64 + lane)) * 8;
            bf16x8 blh = *reinterpret_cast<const bf16x8*>(Wlh + fo);
            bf16x8 bll = *reinterpret_cast<const bf16x8*>(Wll + fo);
            bf16x8 brh = *reinterpret_cast<const bf16x8*>(Wrh + fo);
            bf16x8 brl = *reinterpret_cast<const bf16x8*>(Wrl + fo);
            acc[nt] = __builtin_amdgcn_mfma_f32_16x16x32_bf16(a0h, blh, acc[nt], 0, 0, 0);
            acc[nt] = __builtin_amdgcn_mfma_f32_16x16x32_bf16(a0l, blh, acc[nt], 0, 0, 0);
            acc[nt] = __builtin_amdgcn_mfma_f32_16x16x32_bf16(a0h, bll, acc[nt], 0, 0, 0);
            acc[nt] = __builtin_amdgcn_mfma_f32_16x16x32_bf16(a1, brh, acc[nt], 0, 0, 0);
            acc[nt] = __builtin_amdgcn_mfma_f32_16x16x32_bf16(a1, brl, acc[nt], 0, 0, 0);
        }
    }

    // Epilogue: bias (+relu) + bf16 store. acc[nt][j]: row=(lane>>4)*4+j, col=lane&15.
    const int n0 = lane & 15;
    const int rg = (lane >> 4) * 4;
#pragma unroll
    for (int nt = 0; nt < 8; ++nt) {
        int n = (nh * 8 + nt) * 16 + n0;
        float bias = b[n];
#pragma unroll
        for (int j = 0; j < 4; ++j) {
            int r = row0 + rg + j;
            if (r < NN) {
                float v = acc[nt][j] + bias;
                if (RELU) v = fmaxf(v, 0.0f);
                out[(size_t)r * DD + n] = f2bf(v);
            }
        }
    }
}

// ---------------------------------------------------------------------------
// Predictor: h = x2[a]*x2[b] (bf16) -> cooperative MFMA GEMM -> bias/relu/
// Wp2-dot/sigmoid. Block = 64 queries, 4 waves; wave w owns cols w*64..+63.
// LDS h-tile: unpadded 512B rows + XOR swizzle (byte ^= (row&7)<<4) to kill
// ds_read_b128 bank conflicts (T2/G4 pattern).
__global__ __launch_bounds__(256) void k_pred(const int* __restrict__ edges,
                                              const unsigned short* __restrict__ x2,
                                              const unsigned short* __restrict__ Wp1p,
                                              const float* __restrict__ bp1,
                                              const float* __restrict__ Wp2,
                                              const float* __restrict__ bp2,
                                              float* __restrict__ out) {
    __shared__ unsigned short sh[64 * 256];   // bf16 h tile, swizzled
    __shared__ float psum[4][64];
    const int tid = threadIdx.x;
    const int wave = tid >> 6;
    const int lane = tid & 63;
    const int q0 = blockIdx.x * 64;
    const bool full = (q0 + 64 <= NQ);

    // Gather phase: wave w fills rows w*16..w*16+15 (512B bf16 rows).
    for (int s = 0; s < 16; ++s) {
        int r = wave * 16 + s;
        int q = q0 + r;
        u16x4 pk = {0, 0, 0, 0};
        if (full || q < NQ) {
            int a = edges[q];
            int c = edges[NQ + q];
            u16x4 ua = *reinterpret_cast<const u16x4*>(x2 + (size_t)a * DD + lane * 4);
            u16x4 uc = *reinterpret_cast<const u16x4*>(x2 + (size_t)c * DD + lane * 4);
#pragma unroll
            for (int i = 0; i < 4; ++i) pk[i] = f2bf(bf2f(ua[i]) * bf2f(uc[i]));
        }
        int idx = r * 256 + ((lane * 4) ^ ((r & 7) << 3));   // shorts; 8B aligned
        *reinterpret_cast<u16x4*>(&sh[idx]) = pk;
    }
    __syncthreads();

    // GEMM: wave handles nt = wave*4..wave*4+3 for all 4 row-tiles.
    f32x4 acc[4][4];   // [mtile][ntl]
#pragma unroll
    for (int m = 0; m < 4; ++m)
#pragma unroll
        for (int n = 0; n < 4; ++n) acc[m][n] = {0, 0, 0, 0};

    const int akoff = (lane >> 4) * 8;   // shorts within K-tile
    const int arl = lane & 15;
    for (int kt = 0; kt < 8; ++kt) {
        bf16x8 af[4];
#pragma unroll
        for (int m = 0; m < 4; ++m) {
            int row = m * 16 + arl;
            int idx = row * 256 + ((kt * 32 + akoff) ^ ((row & 7) << 3));
            af[m] = *reinterpret_cast<const bf16x8*>(&sh[idx]);
        }
#pragma unroll
        for (int ntl = 0; ntl < 4; ++ntl) {
            int nt = wave * 4 + ntl;
            bf16x8 bfrag = *reinterpret_cast<const bf16x8*>(
                Wp1p + ((size_t)((kt * 16 + nt) * 64 + lane)) * 8);
#pragma unroll
            for (int m = 0; m < 4; ++m)
                acc[m][ntl] = __builtin_amdgcn_mfma_f32_16x16x32_bf16(af[m], bfrag, acc[m][ntl], 0, 0, 0);
        }
    }

    // Epilogue: bias+relu+Wp2 partial dot within wave's 64 cols.
    float rs[4][4];   // [m][j]
#pragma unroll
    for (int m = 0; m < 4; ++m)
#pragma unroll
        for (int j = 0; j < 4; ++j) rs[m][j] = 0.0f;
#pragma unroll
    for (int ntl = 0; ntl < 4; ++ntl) {
        int n = (wave * 4 + ntl) * 16 + (lane & 15);
        float bias = bp1[n];
        float w2 = Wp2[n];
#pragma unroll
        for (int m = 0; m < 4; ++m)
#pragma unroll
            for (int j = 0; j < 4; ++j)
                rs[m][j] += fmaxf(acc[m][ntl][j] + bias, 0.0f) * w2;
    }
#pragma unroll
    for (int msk = 1; msk < 16; msk <<= 1) {
#pragma unroll
        for (int m = 0; m < 4; ++m)
#pragma unroll
            for (int j = 0; j < 4; ++j) rs[m][j] += __shfl_xor(rs[m][j], msk);
    }
    if ((lane & 15) == 0) {
        int rg = (lane >> 4) * 4;
#pragma unroll
        for (int m = 0; m < 4; ++m)
#pragma unroll
            for (int j = 0; j < 4; ++j)
                psum[wave][m * 16 + rg + j] = rs[m][j];
    }
    __syncthreads();

    if (tid < 64) {
        int q = q0 + tid;
        if (q < NQ) {
            float z = psum[0][tid] + psum[1][tid] + psum[2][tid] + psum[3][tid] + bp2[0];
            out[q] = 1.0f / (1.0f + expf(-z));
        }
    }
}

// ---------------------------------------------------------------------------
extern "C" void kernel_launch(void* const* d_in, const int* in_sizes, int n_in,
                              void* d_out, int out_size, void* d_ws, size_t ws_size,
                              hipStream_t stream) {
    const int*   adj_row = (const int*)d_in[0];
    const int*   adj_col = (const int*)d_in[1];
    const int*   edges   = (const int*)d_in[2];
    const float* emb     = (const float*)d_in[3];
    const float* W1l     = (const float*)d_in[4];
    const float* b1      = (const float*)d_in[5];
    const float* W1r     = (const float*)d_in[6];
    const float* W2l     = (const float*)d_in[7];
    const float* b2      = (const float*)d_in[8];
    const float* W2r     = (const float*)d_in[9];
    const float* Wp1     = (const float*)d_in[10];
    const float* bp1     = (const float*)d_in[11];
    const float* Wp2     = (const float*)d_in[12];
    const float* bp2     = (const float*)d_in[13];
    float* out = (float*)d_out;

    const size_t featF = (size_t)NN * DD * 4;   // 20.48 MB
    const size_t featH = (size_t)NN * DD * 2;   // 10.24 MB
    const size_t packBytes = (size_t)DD * DD * 2;

    char* ws = (char*)d_ws;
    size_t off = 0;
    float*          agg = (float*)(ws + off);          off += featF;
    unsigned short* x1  = (unsigned short*)(ws + off); off += featH;
    unsigned short* xh  = (unsigned short*)(ws + off); off += featH;  // emb_bf16, later x2
    int*   deg    = (int*)(ws + off);   off += (size_t)NN * 4;
    int*   offs   = (int*)(ws + off);   off += (size_t)(NN + 1) * 4;
    int*   cursor = (int*)(ws + off);   off += (size_t)NN * 4;
    float* recip  = (float*)(ws + off); off += (size_t)NN * 4;
    int*   bsum   = (int*)(ws + off);   off += (size_t)NB * 4;
    int*   scol   = (int*)(ws + off);   off += (size_t)NE * 4;
    unsigned short* Wp1p = (unsigned short*)(ws + off); off += packBytes;
    unsigned short* pk[8];   // W1l,W1r,W2l,W2r x {hi,lo}
    for (int i = 0; i < 8; ++i) { pk[i] = (unsigned short*)(ws + off); off += packBytes; }

    const int MB = (NN + 63) / 64;   // 313 M-blocks of 64 rows

    // emb -> bf16 (independent of CSR chain)
    k_cast<<<(NN * DD / 8 + 255) / 256, 256, 0, stream>>>(emb, xh);

    // Build CSR (parallel scan) + pack all weights
    hipMemsetAsync(deg, 0, NN * 4, stream);
    k_deg<<<(NE + 255) / 256, 256, 0, stream>>>(adj_row, deg);
    k_scan1<<<NB, 256, 0, stream>>>(deg, offs, bsum);
    k_scan2<<<1, 256, 0, stream>>>(bsum);
    k_scan3<<<NB, 256, 0, stream>>>(deg, bsum, offs, cursor, recip);
    k_fill<<<(NE + 255) / 256, 256, 0, stream>>>(adj_row, adj_col, cursor, scol);
    k_packs<<<160, 256, 0, stream>>>(W1l, W1r, W2l, W2r, Wp1,
                                     pk[0], pk[2], pk[4], pk[6], Wp1p,
                                     pk[1], pk[3], pk[5], pk[7]);

    // Layer 1: bf16 gather of emb_bf16; A1 = emb_bf16; out x1 bf16.
    k_agg_h<<<(NN + 3) / 4, 256, 0, stream>>>(offs, scol, recip, xh, agg);
    k_sagem<1><<<MB * 2, 256, 0, stream>>>(agg, xh,
                                           pk[0], pk[1], pk[2], pk[3], b1, x1);

    // Layer 2: bf16 gather of x1; A1 = x1; out x2 (reuses emb_bf16 buffer).
    unsigned short* x2 = xh;   // emb_bf16 dead after layer-1 GEMM
    k_agg_h<<<(NN + 3) / 4, 256, 0, stream>>>(offs, scol, recip, x1, agg);
    k_sagem<0><<<MB * 2, 256, 0, stream>>>(agg, x1,
                                           pk[4], pk[5], pk[6], pk[7], b2, x2);

    // Predictor (cooperative bf16 MFMA, swizzled LDS)
    k_pred<<<(NQ + 63) / 64, 256, 0, stream>>>(edges, x2, Wp1p, bp1, Wp2, bp2, out);
}

// Round 8
// 259.303 us; speedup vs baseline: 1.9362x; 1.2877x over previous
//
#include <hip/hip_runtime.h>
#include <cstddef>

// Problem constants (match reference)
constexpr int NN = 20000;    // nodes
constexpr int NE = 320000;   // edges
constexpr int NQ = 100000;   // queries
constexpr int DD = 256;      // feature dim
constexpr int NB = (NN + 255) / 256;   // scan blocks (79)

typedef __attribute__((ext_vector_type(8))) short bf16x8;
typedef __attribute__((ext_vector_type(4))) float f32x4;
typedef __attribute__((ext_vector_type(4))) unsigned short u16x4;
typedef __attribute__((ext_vector_type(8))) unsigned short u16x8;

__device__ inline unsigned short f2bf(float f) {
    union { float f; unsigned u; } v; v.f = f;
    unsigned r = v.u + 0x7fffu + ((v.u >> 16) & 1u);   // RNE
    return (unsigned short)(r >> 16);
}
__device__ inline float bf2f(unsigned short h) {
    union { unsigned u; float f; } t; t.u = ((unsigned)h) << 16;
    return t.f;
}

// ---------------------------------------------------------------------------
// Cast emb f32 -> bf16 (16B/thread)
__global__ __launch_bounds__(256) void k_cast(const float* __restrict__ x,
                                              unsigned short* __restrict__ y) {
    int i = blockIdx.x * 256 + threadIdx.x;   // 8 elems per thread
    if (i >= NN * DD / 8) return;
    float4 f0 = *reinterpret_cast<const float4*>(x + (size_t)i * 8);
    float4 f1 = *reinterpret_cast<const float4*>(x + (size_t)i * 8 + 4);
    u16x8 o;
    o[0] = f2bf(f0.x); o[1] = f2bf(f0.y); o[2] = f2bf(f0.z); o[3] = f2bf(f0.w);
    o[4] = f2bf(f1.x); o[5] = f2bf(f1.y); o[6] = f2bf(f1.z); o[7] = f2bf(f1.w);
    *reinterpret_cast<u16x8*>(y + (size_t)i * 8) = o;
}

// ---------------------------------------------------------------------------
// Degree histogram (int): deg[row[e]] += 1
__global__ __launch_bounds__(256) void k_deg(const int* __restrict__ row,
                                             int* __restrict__ deg) {
    int e = blockIdx.x * 256 + threadIdx.x;
    if (e < NE) atomicAdd(&deg[row[e]], 1);
}

// Parallel scan, step 1: block-local exclusive scan + block sums.
__global__ __launch_bounds__(256) void k_scan1(const int* __restrict__ deg,
                                               int* __restrict__ offs,
                                               int* __restrict__ bsum) {
    __shared__ int wsum[4];
    const int tid = threadIdx.x, lane = tid & 63, wid = tid >> 6;
    int i = blockIdx.x * 256 + tid;
    int v = (i < NN) ? deg[i] : 0;
    int sc = v;
#pragma unroll
    for (int d = 1; d < 64; d <<= 1) {
        int t = __shfl_up(sc, d);
        if (lane >= d) sc += t;
    }
    if (lane == 63) wsum[wid] = sc;
    __syncthreads();
    int wpre = 0;
    for (int w = 0; w < wid; ++w) wpre += wsum[w];
    if (i < NN) offs[i] = wpre + sc - v;
    if (tid == 255) bsum[blockIdx.x] = wpre + sc;
}

// Step 2: exclusive scan over the NB block sums (single small block).
__global__ __launch_bounds__(256) void k_scan2(int* __restrict__ bsum) {
    __shared__ int wsum[4];
    const int tid = threadIdx.x, lane = tid & 63, wid = tid >> 6;
    int v = (tid < NB) ? bsum[tid] : 0;
    int sc = v;
#pragma unroll
    for (int d = 1; d < 64; d <<= 1) {
        int t = __shfl_up(sc, d);
        if (lane >= d) sc += t;
    }
    if (lane == 63) wsum[wid] = sc;
    __syncthreads();
    int wpre = 0;
    for (int w = 0; w < wid; ++w) wpre += wsum[w];
    if (tid < NB) bsum[tid] = wpre + sc - v;
}

// Step 3: add block prefix; emit cursor + recip; offs[NN] = NE.
__global__ __launch_bounds__(256) void k_scan3(const int* __restrict__ deg,
                                               const int* __restrict__ bsum,
                                               int* __restrict__ offs,
                                               int* __restrict__ cursor,
                                               float* __restrict__ recip) {
    int i = blockIdx.x * 256 + threadIdx.x;
    if (i < NN) {
        int o = offs[i] + bsum[i >> 8];
        offs[i] = o;
        cursor[i] = o;
        recip[i] = 1.0f / fmaxf((float)deg[i], 1.0f);
    }
    if (i == 0) offs[NN] = NE;
}

// Fill CSR adjacency: scol[cursor[row[e]]++] = col[e]
__global__ __launch_bounds__(256) void k_fill(const int* __restrict__ row,
                                              const int* __restrict__ col,
                                              int* __restrict__ cursor,
                                              int* __restrict__ scol) {
    int e = blockIdx.x * 256 + threadIdx.x;
    if (e < NE) {
        int r = row[e];
        int p = atomicAdd(&cursor[r], 1);
        scol[p] = col[e];
    }
}

// ---------------------------------------------------------------------------
// Gather-aggregate (mean), bf16 source, output split hi/lo bf16.
// One wave per node; 2 neighbors in parallel (lane>>5 selects), 16B loads,
// x2 unroll = 4 neighbors in flight. Final merge via shfl_xor(32).
__global__ __launch_bounds__(256) void k_agg_hl(const int* __restrict__ offs,
                                                const int* __restrict__ scol,
                                                const float* __restrict__ recip,
                                                const unsigned short* __restrict__ x,
                                                unsigned short* __restrict__ aggH,
                                                unsigned short* __restrict__ aggL) {
    int node = blockIdx.x * 4 + (threadIdx.x >> 6);
    int lane = threadIdx.x & 63;
    if (node >= NN) return;
    int s = offs[node];
    int e = offs[node + 1];
    const int half = lane >> 5;      // 0/1: which neighbor of the pair
    const int l32 = lane & 31;       // 8-elem column group
    float acc[8] = {0, 0, 0, 0, 0, 0, 0, 0};
    float acc2[8] = {0, 0, 0, 0, 0, 0, 0, 0};
    int p = s;
    for (; p + 3 < e; p += 4) {
        int c0 = scol[p + half];
        int c1 = scol[p + 2 + half];
        u16x8 v0 = *reinterpret_cast<const u16x8*>(x + (size_t)c0 * DD + l32 * 8);
        u16x8 v1 = *reinterpret_cast<const u16x8*>(x + (size_t)c1 * DD + l32 * 8);
#pragma unroll
        for (int i = 0; i < 8; ++i) {
            acc[i] += bf2f(v0[i]);
            acc2[i] += bf2f(v1[i]);
        }
    }
    for (; p + 1 < e; p += 2) {
        int c0 = scol[p + half];
        u16x8 v0 = *reinterpret_cast<const u16x8*>(x + (size_t)c0 * DD + l32 * 8);
#pragma unroll
        for (int i = 0; i < 8; ++i) acc[i] += bf2f(v0[i]);
    }
    if (p < e && half == 0) {   // single leftover neighbor
        int c0 = scol[p];
        u16x8 v0 = *reinterpret_cast<const u16x8*>(x + (size_t)c0 * DD + l32 * 8);
#pragma unroll
        for (int i = 0; i < 8; ++i) acc2[i] += bf2f(v0[i]);
    }
    float rc = recip[node];
    u16x8 hi, lo;
#pragma unroll
    for (int i = 0; i < 8; ++i) {
        float t = acc[i] + acc2[i];
        t += __shfl_xor(t, 32);
        t *= rc;
        unsigned short h = f2bf(t);
        hi[i] = h;
        lo[i] = f2bf(t - bf2f(h));
    }
    if (half == 0) {
        *reinterpret_cast<u16x8*>(aggH + (size_t)node * DD + l32 * 8) = hi;
        *reinterpret_cast<u16x8*>(aggL + (size_t)node * DD + l32 * 8) = lo;
    }
}

// ---------------------------------------------------------------------------
// Pack 5 f32 256x256 matrices into bf16 MFMA B-fragment layout.
// m = 0..3: hi + lo split (W1l,W1r,W2l,W2r). m = 4: hi only (Wp1).
__global__ __launch_bounds__(256) void k_packs(
    const float* __restrict__ w0, const float* __restrict__ w1,
    const float* __restrict__ w2, const float* __restrict__ w3,
    const float* __restrict__ w4,
    unsigned short* __restrict__ h0, unsigned short* __restrict__ h1,
    unsigned short* __restrict__ h2, unsigned short* __restrict__ h3,
    unsigned short* __restrict__ h4,
    unsigned short* __restrict__ l0, unsigned short* __restrict__ l1,
    unsigned short* __restrict__ l2, unsigned short* __restrict__ l3) {
    int m = blockIdx.x >> 5;
    int idx = (blockIdx.x & 31) * 256 + threadIdx.x;   // 0..8191
    const float* W = (m == 0) ? w0 : (m == 1) ? w1 : (m == 2) ? w2 : (m == 3) ? w3 : w4;
    unsigned short* H = (m == 0) ? h0 : (m == 1) ? h1 : (m == 2) ? h2 : (m == 3) ? h3 : h4;
    unsigned short* L = (m == 0) ? l0 : (m == 1) ? l1 : (m == 2) ? l2 : (m == 3) ? l3 : nullptr;
    int t = idx >> 6, lane = idx & 63;
    int kt = t >> 4, nt = t & 15;
    int k0 = kt * 32 + (lane >> 4) * 8;
    int n = nt * 16 + (lane & 15);
    unsigned uh[4], ul[4];
#pragma unroll
    for (int i = 0; i < 4; ++i) {
        float fa = W[(size_t)(k0 + 2 * i) * DD + n];
        float fb = W[(size_t)(k0 + 2 * i + 1) * DD + n];
        unsigned short ha = f2bf(fa), hb = f2bf(fb);
        unsigned short la = f2bf(fa - bf2f(ha)), lb = f2bf(fb - bf2f(hb));
        uh[i] = (unsigned)ha | ((unsigned)hb << 16);
        ul[i] = (unsigned)la | ((unsigned)lb << 16);
    }
    *reinterpret_cast<uint4*>(H + (size_t)idx * 8) = make_uint4(uh[0], uh[1], uh[2], uh[3]);
    if (L)
        *reinterpret_cast<uint4*>(L + (size_t)idx * 8) = make_uint4(ul[0], ul[1], ul[2], ul[3]);
}

// ---------------------------------------------------------------------------
// MFMA SAGE layer: out_bf16 = [relu]( (aggH+aggL) @ Wl + b + A1 @ Wr ).
// All A operands are direct bf16 fragment loads (no conversion VALU).
// Wave = one 16-row M-tile x 128 cols (N-split). Block = 4 waves = 64 rows.
template <int RELU>
__global__ __launch_bounds__(256) void k_sagem(
    const unsigned short* __restrict__ aggH, const unsigned short* __restrict__ aggL,
    const unsigned short* __restrict__ A1h,
    const unsigned short* __restrict__ Wlh, const unsigned short* __restrict__ Wll,
    const unsigned short* __restrict__ Wrh, const unsigned short* __restrict__ Wrl,
    const float* __restrict__ b, unsigned short* __restrict__ out) {
    const int nh   = blockIdx.x & 1;
    const int mblk = blockIdx.x >> 1;
    const int wave = threadIdx.x >> 6;
    const int lane = threadIdx.x & 63;
    const int row0 = mblk * 64 + wave * 16;
    const int kcol = (lane >> 4) * 8;
    const int ar = min(row0 + (lane & 15), NN - 1);

    f32x4 acc[8];
#pragma unroll
    for (int nt = 0; nt < 8; ++nt) acc[nt] = {0, 0, 0, 0};

#pragma unroll 2
    for (int kt = 0; kt < 8; ++kt) {
        const size_t ao = (size_t)ar * DD + kt * 32 + kcol;
        bf16x8 a0h = *reinterpret_cast<const bf16x8*>(aggH + ao);
        bf16x8 a0l = *reinterpret_cast<const bf16x8*>(aggL + ao);
        bf16x8 a1  = *reinterpret_cast<const bf16x8*>(A1h + ao);
#pragma unroll
        for (int nt = 0; nt < 8; ++nt) {
            const size_t fo = ((size_t)((kt * 16 + nh * 8 + nt) * 64 + lane)) * 8;
            bf16x8 blh = *reinterpret_cast<const bf16x8*>(Wlh + fo);
            bf16x8 bll = *reinterpret_cast<const bf16x8*>(Wll + fo);
            bf16x8 brh = *reinterpret_cast<const bf16x8*>(Wrh + fo);
            bf16x8 brl = *reinterpret_cast<const bf16x8*>(Wrl + fo);
            acc[nt] = __builtin_amdgcn_mfma_f32_16x16x32_bf16(a0h, blh, acc[nt], 0, 0, 0);
            acc[nt] = __builtin_amdgcn_mfma_f32_16x16x32_bf16(a0l, blh, acc[nt], 0, 0, 0);
            acc[nt] = __builtin_amdgcn_mfma_f32_16x16x32_bf16(a0h, bll, acc[nt], 0, 0, 0);
            acc[nt] = __builtin_amdgcn_mfma_f32_16x16x32_bf16(a1, brh, acc[nt], 0, 0, 0);
            acc[nt] = __builtin_amdgcn_mfma_f32_16x16x32_bf16(a1, brl, acc[nt], 0, 0, 0);
        }
    }

    // Epilogue: bias (+relu) + bf16 store. acc[nt][j]: row=(lane>>4)*4+j, col=lane&15.
    const int n0 = lane & 15;
    const int rg = (lane >> 4) * 4;
#pragma unroll
    for (int nt = 0; nt < 8; ++nt) {
        int n = (nh * 8 + nt) * 16 + n0;
        float bias = b[n];
#pragma unroll
        for (int j = 0; j < 4; ++j) {
            int r = row0 + rg + j;
            if (r < NN) {
                float v = acc[nt][j] + bias;
                if (RELU) v = fmaxf(v, 0.0f);
                out[(size_t)r * DD + n] = f2bf(v);
            }
        }
    }
}

// ---------------------------------------------------------------------------
// Predictor: 512 threads = 8 waves, 128 queries/block.
// Gather: 16 threads/row x 4 steps (parallel, 16B loads), swizzled LDS.
// GEMM: cooperative N-split, wave w owns cols w*32..w*32+31 (2 nt).
// psum aliases the LDS h-tile (dead after GEMM reads).
__global__ __launch_bounds__(512, 4) void k_pred(const int* __restrict__ edges,
                                                 const unsigned short* __restrict__ x2,
                                                 const unsigned short* __restrict__ Wp1p,
                                                 const float* __restrict__ bp1,
                                                 const float* __restrict__ Wp2,
                                                 const float* __restrict__ bp2,
                                                 float* __restrict__ out) {
    __shared__ unsigned short sh[128 * 256];   // 64KB bf16 h tile, swizzled
    const int tid = threadIdx.x;
    const int wave = tid >> 6;
    const int lane = tid & 63;
    const int q0 = blockIdx.x * 128;

    // Gather: step s covers rows s*32..s*32+31; 16 threads per row.
    const int grow = tid >> 4;         // 0..31
    const int t16 = tid & 15;
#pragma unroll
    for (int s = 0; s < 4; ++s) {
        int r = s * 32 + grow;
        int q = q0 + r;
        u16x8 p0 = {0, 0, 0, 0, 0, 0, 0, 0};
        u16x8 p1 = {0, 0, 0, 0, 0, 0, 0, 0};
        if (q < NQ) {
            int a = edges[q];
            int c = edges[NQ + q];
            const unsigned short* pa = x2 + (size_t)a * DD + t16 * 16;
            const unsigned short* pc = x2 + (size_t)c * DD + t16 * 16;
            u16x8 ua0 = *reinterpret_cast<const u16x8*>(pa);
            u16x8 ua1 = *reinterpret_cast<const u16x8*>(pa + 8);
            u16x8 uc0 = *reinterpret_cast<const u16x8*>(pc);
            u16x8 uc1 = *reinterpret_cast<const u16x8*>(pc + 8);
#pragma unroll
            for (int i = 0; i < 8; ++i) {
                p0[i] = f2bf(bf2f(ua0[i]) * bf2f(uc0[i]));
                p1[i] = f2bf(bf2f(ua1[i]) * bf2f(uc1[i]));
            }
        }
        int swz = (r & 7) << 3;
        *reinterpret_cast<u16x8*>(&sh[r * 256 + ((t16 * 16) ^ swz)]) = p0;
        *reinterpret_cast<u16x8*>(&sh[r * 256 + ((t16 * 16 + 8) ^ swz)]) = p1;
    }
    __syncthreads();

    // GEMM: wave owns nt = wave*2, wave*2+1; 8 row-tiles.
    f32x4 acc[8][2];
#pragma unroll
    for (int m = 0; m < 8; ++m)
#pragma unroll
        for (int n = 0; n < 2; ++n) acc[m][n] = {0, 0, 0, 0};

    const int akoff = (lane >> 4) * 8;
    const int arl = lane & 15;
    for (int kt = 0; kt < 8; ++kt) {
        bf16x8 af[8];
#pragma unroll
        for (int m = 0; m < 8; ++m) {
            int row = m * 16 + arl;
            af[m] = *reinterpret_cast<const bf16x8*>(
                &sh[row * 256 + ((kt * 32 + akoff) ^ ((row & 7) << 3))]);
        }
#pragma unroll
        for (int ntl = 0; ntl < 2; ++ntl) {
            int nt = wave * 2 + ntl;
            bf16x8 bfrag = *reinterpret_cast<const bf16x8*>(
                Wp1p + ((size_t)((kt * 16 + nt) * 64 + lane)) * 8);
#pragma unroll
            for (int m = 0; m < 8; ++m)
                acc[m][ntl] = __builtin_amdgcn_mfma_f32_16x16x32_bf16(af[m], bfrag, acc[m][ntl], 0, 0, 0);
        }
    }

    // Epilogue: bias+relu+Wp2 partial dot within wave's 32 cols.
    float rs[8][4];
#pragma unroll
    for (int m = 0; m < 8; ++m)
#pragma unroll
        for (int j = 0; j < 4; ++j) rs[m][j] = 0.0f;
#pragma unroll
    for (int ntl = 0; ntl < 2; ++ntl) {
        int n = (wave * 2 + ntl) * 16 + (lane & 15);
        float bias = bp1[n];
        float w2 = Wp2[n];
#pragma unroll
        for (int m = 0; m < 8; ++m)
#pragma unroll
            for (int j = 0; j < 4; ++j)
                rs[m][j] += fmaxf(acc[m][ntl][j] + bias, 0.0f) * w2;
    }
#pragma unroll
    for (int msk = 1; msk < 16; msk <<= 1) {
#pragma unroll
        for (int m = 0; m < 8; ++m)
#pragma unroll
            for (int j = 0; j < 4; ++j) rs[m][j] += __shfl_xor(rs[m][j], msk);
    }

    // psum aliases sh (all sh reads are done; barrier makes it safe).
    float* psum = reinterpret_cast<float*>(sh);   // [8][128]
    __syncthreads();
    if ((lane & 15) == 0) {
        int rg = (lane >> 4) * 4;
#pragma unroll
        for (int m = 0; m < 8; ++m)
#pragma unroll
            for (int j = 0; j < 4; ++j)
                psum[wave * 128 + m * 16 + rg + j] = rs[m][j];
    }
    __syncthreads();

    if (tid < 128) {
        int q = q0 + tid;
        if (q < NQ) {
            float z = bp2[0];
#pragma unroll
            for (int w = 0; w < 8; ++w) z += psum[w * 128 + tid];
            out[q] = 1.0f / (1.0f + expf(-z));
        }
    }
}

// ---------------------------------------------------------------------------
extern "C" void kernel_launch(void* const* d_in, const int* in_sizes, int n_in,
                              void* d_out, int out_size, void* d_ws, size_t ws_size,
                              hipStream_t stream) {
    const int*   adj_row = (const int*)d_in[0];
    const int*   adj_col = (const int*)d_in[1];
    const int*   edges   = (const int*)d_in[2];
    const float* emb     = (const float*)d_in[3];
    const float* W1l     = (const float*)d_in[4];
    const float* b1      = (const float*)d_in[5];
    const float* W1r     = (const float*)d_in[6];
    const float* W2l     = (const float*)d_in[7];
    const float* b2      = (const float*)d_in[8];
    const float* W2r     = (const float*)d_in[9];
    const float* Wp1     = (const float*)d_in[10];
    const float* bp1     = (const float*)d_in[11];
    const float* Wp2     = (const float*)d_in[12];
    const float* bp2     = (const float*)d_in[13];
    float* out = (float*)d_out;

    const size_t featH = (size_t)NN * DD * 2;   // 10.24 MB
    const size_t packBytes = (size_t)DD * DD * 2;

    char* ws = (char*)d_ws;
    size_t off = 0;
    unsigned short* aggH = (unsigned short*)(ws + off); off += featH;
    unsigned short* aggL = (unsigned short*)(ws + off); off += featH;
    unsigned short* x1   = (unsigned short*)(ws + off); off += featH;
    unsigned short* xh   = (unsigned short*)(ws + off); off += featH;  // emb_bf16, later x2
    int*   deg    = (int*)(ws + off);   off += (size_t)NN * 4;
    int*   offs   = (int*)(ws + off);   off += (size_t)(NN + 1) * 4;
    int*   cursor = (int*)(ws + off);   off += (size_t)NN * 4;
    float* recip  = (float*)(ws + off); off += (size_t)NN * 4;
    int*   bsum   = (int*)(ws + off);   off += (size_t)NB * 4;
    int*   scol   = (int*)(ws + off);   off += (size_t)NE * 4;
    unsigned short* Wp1p = (unsigned short*)(ws + off); off += packBytes;
    unsigned short* pk[8];   // W1l,W1r,W2l,W2r x {hi,lo}
    for (int i = 0; i < 8; ++i) { pk[i] = (unsigned short*)(ws + off); off += packBytes; }

    const int MB = (NN + 63) / 64;   // 313 M-blocks of 64 rows

    // emb -> bf16 (independent of CSR chain)
    k_cast<<<(NN * DD / 8 + 255) / 256, 256, 0, stream>>>(emb, xh);

    // Build CSR (parallel scan) + pack all weights
    hipMemsetAsync(deg, 0, NN * 4, stream);
    k_deg<<<(NE + 255) / 256, 256, 0, stream>>>(adj_row, deg);
    k_scan1<<<NB, 256, 0, stream>>>(deg, offs, bsum);
    k_scan2<<<1, 256, 0, stream>>>(bsum);
    k_scan3<<<NB, 256, 0, stream>>>(deg, bsum, offs, cursor, recip);
    k_fill<<<(NE + 255) / 256, 256, 0, stream>>>(adj_row, adj_col, cursor, scol);
    k_packs<<<160, 256, 0, stream>>>(W1l, W1r, W2l, W2r, Wp1,
                                     pk[0], pk[2], pk[4], pk[6], Wp1p,
                                     pk[1], pk[3], pk[5], pk[7]);

    // Layer 1: gather emb_bf16 -> aggH/aggL; A1 = emb_bf16; out x1 bf16.
    k_agg_hl<<<(NN + 3) / 4, 256, 0, stream>>>(offs, scol, recip, xh, aggH, aggL);
    k_sagem<1><<<MB * 2, 256, 0, stream>>>(aggH, aggL, xh,
                                           pk[0], pk[1], pk[2], pk[3], b1, x1);

    // Layer 2: gather x1 -> aggH/aggL; A1 = x1; out x2 (reuses emb_bf16 buffer).
    unsigned short* x2 = xh;   // emb_bf16 dead after layer-1 GEMM
    k_agg_hl<<<(NN + 3) / 4, 256, 0, stream>>>(offs, scol, recip, x1, aggH, aggL);
    k_sagem<0><<<MB * 2, 256, 0, stream>>>(aggH, aggL, x1,
                                           pk[4], pk[5], pk[6], pk[7], b2, x2);

    // Predictor (512-thread cooperative bf16 MFMA, parallel gather)
    k_pred<<<(NQ + 127) / 128, 512, 0, stream>>>(edges, x2, Wp1p, bp1, Wp2, bp2, out);
}

// Round 9
// 197.294 us; speedup vs baseline: 2.5448x; 1.3143x over previous
//
#include <hip/hip_runtime.h>
#include <cstddef>

// Problem constants (match reference)
constexpr int NN = 20000;    // nodes
constexpr int NE = 320000;   // edges
constexpr int NQ = 100000;   // queries
constexpr int DD = 256;      // feature dim
constexpr int NB = (NN + 255) / 256;   // scan blocks (79)

typedef __attribute__((ext_vector_type(8))) short bf16x8;
typedef __attribute__((ext_vector_type(4))) float f32x4;
typedef __attribute__((ext_vector_type(4))) unsigned short u16x4;
typedef __attribute__((ext_vector_type(8))) unsigned short u16x8;

__device__ inline unsigned short f2bf(float f) {
    union { float f; unsigned u; } v; v.f = f;
    unsigned r = v.u + 0x7fffu + ((v.u >> 16) & 1u);   // RNE
    return (unsigned short)(r >> 16);
}
__device__ inline float bf2f(unsigned short h) {
    union { unsigned u; float f; } t; t.u = ((unsigned)h) << 16;
    return t.f;
}

// ---------------------------------------------------------------------------
// Cast emb f32 -> bf16 (16B/thread)
__global__ __launch_bounds__(256) void k_cast(const float* __restrict__ x,
                                              unsigned short* __restrict__ y) {
    int i = blockIdx.x * 256 + threadIdx.x;   // 8 elems per thread
    if (i >= NN * DD / 8) return;
    float4 f0 = *reinterpret_cast<const float4*>(x + (size_t)i * 8);
    float4 f1 = *reinterpret_cast<const float4*>(x + (size_t)i * 8 + 4);
    u16x8 o;
    o[0] = f2bf(f0.x); o[1] = f2bf(f0.y); o[2] = f2bf(f0.z); o[3] = f2bf(f0.w);
    o[4] = f2bf(f1.x); o[5] = f2bf(f1.y); o[6] = f2bf(f1.z); o[7] = f2bf(f1.w);
    *reinterpret_cast<u16x8*>(y + (size_t)i * 8) = o;
}

// ---------------------------------------------------------------------------
// Degree histogram (int): deg[row[e]] += 1
__global__ __launch_bounds__(256) void k_deg(const int* __restrict__ row,
                                             int* __restrict__ deg) {
    int e = blockIdx.x * 256 + threadIdx.x;
    if (e < NE) atomicAdd(&deg[row[e]], 1);
}

// Parallel scan, step 1: block-local exclusive scan + block sums.
__global__ __launch_bounds__(256) void k_scan1(const int* __restrict__ deg,
                                               int* __restrict__ offs,
                                               int* __restrict__ bsum) {
    __shared__ int wsum[4];
    const int tid = threadIdx.x, lane = tid & 63, wid = tid >> 6;
    int i = blockIdx.x * 256 + tid;
    int v = (i < NN) ? deg[i] : 0;
    int sc = v;
#pragma unroll
    for (int d = 1; d < 64; d <<= 1) {
        int t = __shfl_up(sc, d);
        if (lane >= d) sc += t;
    }
    if (lane == 63) wsum[wid] = sc;
    __syncthreads();
    int wpre = 0;
    for (int w = 0; w < wid; ++w) wpre += wsum[w];
    if (i < NN) offs[i] = wpre + sc - v;
    if (tid == 255) bsum[blockIdx.x] = wpre + sc;
}

// Step 2: exclusive scan over the NB block sums (single small block).
__global__ __launch_bounds__(256) void k_scan2(int* __restrict__ bsum) {
    __shared__ int wsum[4];
    const int tid = threadIdx.x, lane = tid & 63, wid = tid >> 6;
    int v = (tid < NB) ? bsum[tid] : 0;
    int sc = v;
#pragma unroll
    for (int d = 1; d < 64; d <<= 1) {
        int t = __shfl_up(sc, d);
        if (lane >= d) sc += t;
    }
    if (lane == 63) wsum[wid] = sc;
    __syncthreads();
    int wpre = 0;
    for (int w = 0; w < wid; ++w) wpre += wsum[w];
    if (tid < NB) bsum[tid] = wpre + sc - v;
}

// Step 3: add block prefix; emit cursor + recip; offs[NN] = NE.
__global__ __launch_bounds__(256) void k_scan3(const int* __restrict__ deg,
                                               const int* __restrict__ bsum,
                                               int* __restrict__ offs,
                                               int* __restrict__ cursor,
                                               float* __restrict__ recip) {
    int i = blockIdx.x * 256 + threadIdx.x;
    if (i < NN) {
        int o = offs[i] + bsum[i >> 8];
        offs[i] = o;
        cursor[i] = o;
        recip[i] = 1.0f / fmaxf((float)deg[i], 1.0f);
    }
    if (i == 0) offs[NN] = NE;
}

// Fill CSR adjacency: scol[cursor[row[e]]++] = col[e]
__global__ __launch_bounds__(256) void k_fill(const int* __restrict__ row,
                                              const int* __restrict__ col,
                                              int* __restrict__ cursor,
                                              int* __restrict__ scol) {
    int e = blockIdx.x * 256 + threadIdx.x;
    if (e < NE) {
        int r = row[e];
        int p = atomicAdd(&cursor[r], 1);
        scol[p] = col[e];
    }
}

// ---------------------------------------------------------------------------
// Pack 5 f32 256x256 matrices into bf16 MFMA B-fragment layout.
// m = 0..3: hi + lo split (W1l,W1r,W2l,W2r). m = 4: hi only (Wp1).
__global__ __launch_bounds__(256) void k_packs(
    const float* __restrict__ w0, const float* __restrict__ w1,
    const float* __restrict__ w2, const float* __restrict__ w3,
    const float* __restrict__ w4,
    unsigned short* __restrict__ h0, unsigned short* __restrict__ h1,
    unsigned short* __restrict__ h2, unsigned short* __restrict__ h3,
    unsigned short* __restrict__ h4,
    unsigned short* __restrict__ l0, unsigned short* __restrict__ l1,
    unsigned short* __restrict__ l2, unsigned short* __restrict__ l3) {
    int m = blockIdx.x >> 5;
    int idx = (blockIdx.x & 31) * 256 + threadIdx.x;   // 0..8191
    const float* W = (m == 0) ? w0 : (m == 1) ? w1 : (m == 2) ? w2 : (m == 3) ? w3 : w4;
    unsigned short* H = (m == 0) ? h0 : (m == 1) ? h1 : (m == 2) ? h2 : (m == 3) ? h3 : h4;
    unsigned short* L = (m == 0) ? l0 : (m == 1) ? l1 : (m == 2) ? l2 : (m == 3) ? l3 : nullptr;
    int t = idx >> 6, lane = idx & 63;
    int kt = t >> 4, nt = t & 15;
    int k0 = kt * 32 + (lane >> 4) * 8;
    int n = nt * 16 + (lane & 15);
    unsigned uh[4], ul[4];
#pragma unroll
    for (int i = 0; i < 4; ++i) {
        float fa = W[(size_t)(k0 + 2 * i) * DD + n];
        float fb = W[(size_t)(k0 + 2 * i + 1) * DD + n];
        unsigned short ha = f2bf(fa), hb = f2bf(fb);
        unsigned short la = f2bf(fa - bf2f(ha)), lb = f2bf(fb - bf2f(hb));
        uh[i] = (unsigned)ha | ((unsigned)hb << 16);
        ul[i] = (unsigned)la | ((unsigned)lb << 16);
    }
    *reinterpret_cast<uint4*>(H + (size_t)idx * 8) = make_uint4(uh[0], uh[1], uh[2], uh[3]);
    if (L)
        *reinterpret_cast<uint4*>(L + (size_t)idx * 8) = make_uint4(ul[0], ul[1], ul[2], ul[3]);
}

// ---------------------------------------------------------------------------
// Dense dual GEMM: P = A @ Wl, Q = A @ Wr (A exact bf16; weights hi+lo ->
// 2 MFMA terms each). Mean-aggregation is deferred to k_gath (linearity).
// Wave = one 16-row M-tile x 64 cols (N-quarter). Block = 4 waves = 64 rows.
// blockIdx = mblk*4 + nquarter.
__global__ __launch_bounds__(256) void k_lin(
    const unsigned short* __restrict__ A,
    const unsigned short* __restrict__ Wlh, const unsigned short* __restrict__ Wll,
    const unsigned short* __restrict__ Wrh, const unsigned short* __restrict__ Wrl,
    unsigned short* __restrict__ P, unsigned short* __restrict__ Q) {
    const int nq   = blockIdx.x & 3;
    const int mblk = blockIdx.x >> 2;
    const int wave = threadIdx.x >> 6;
    const int lane = threadIdx.x & 63;
    const int row0 = mblk * 64 + wave * 16;
    const int kcol = (lane >> 4) * 8;
    const int ar = min(row0 + (lane & 15), NN - 1);

    f32x4 accP[4], accQ[4];
#pragma unroll
    for (int nt = 0; nt < 4; ++nt) {
        accP[nt] = {0, 0, 0, 0};
        accQ[nt] = {0, 0, 0, 0};
    }

#pragma unroll 2
    for (int kt = 0; kt < 8; ++kt) {
        bf16x8 a1 = *reinterpret_cast<const bf16x8*>(A + (size_t)ar * DD + kt * 32 + kcol);
#pragma unroll
        for (int nt = 0; nt < 4; ++nt) {
            const size_t fo = ((size_t)((kt * 16 + nq * 4 + nt) * 64 + lane)) * 8;
            bf16x8 blh = *reinterpret_cast<const bf16x8*>(Wlh + fo);
            bf16x8 bll = *reinterpret_cast<const bf16x8*>(Wll + fo);
            bf16x8 brh = *reinterpret_cast<const bf16x8*>(Wrh + fo);
            bf16x8 brl = *reinterpret_cast<const bf16x8*>(Wrl + fo);
            accP[nt] = __builtin_amdgcn_mfma_f32_16x16x32_bf16(a1, blh, accP[nt], 0, 0, 0);
            accP[nt] = __builtin_amdgcn_mfma_f32_16x16x32_bf16(a1, bll, accP[nt], 0, 0, 0);
            accQ[nt] = __builtin_amdgcn_mfma_f32_16x16x32_bf16(a1, brh, accQ[nt], 0, 0, 0);
            accQ[nt] = __builtin_amdgcn_mfma_f32_16x16x32_bf16(a1, brl, accQ[nt], 0, 0, 0);
        }
    }

    // Store. acc[nt][j]: row = (lane>>4)*4+j, col = (nq*4+nt)*16 + (lane&15).
    const int n0 = lane & 15;
    const int rg = (lane >> 4) * 4;
#pragma unroll
    for (int nt = 0; nt < 4; ++nt) {
        int n = (nq * 4 + nt) * 16 + n0;
#pragma unroll
        for (int j = 0; j < 4; ++j) {
            int r = row0 + rg + j;
            if (r < NN) {
                P[(size_t)r * DD + n] = f2bf(accP[nt][j]);
                Q[(size_t)r * DD + n] = f2bf(accQ[nt][j]);
            }
        }
    }
}

// ---------------------------------------------------------------------------
// Gather + epilogue: out[i] = [relu]( recip[i]*sum_{c in N(i)} P[c,:]
//                                     + Q[i,:] + b )   (bf16 out)
// One wave per node; 2 neighbors in parallel (lane>>5), 16B loads.
template <int RELU>
__global__ __launch_bounds__(256) void k_gath(const int* __restrict__ offs,
                                              const int* __restrict__ scol,
                                              const float* __restrict__ recip,
                                              const unsigned short* __restrict__ P,
                                              const unsigned short* __restrict__ Q,
                                              const float* __restrict__ b,
                                              unsigned short* __restrict__ out) {
    int node = blockIdx.x * 4 + (threadIdx.x >> 6);
    int lane = threadIdx.x & 63;
    if (node >= NN) return;
    int s = offs[node];
    int e = offs[node + 1];
    const int half = lane >> 5;
    const int l32 = lane & 31;
    float acc[8] = {0, 0, 0, 0, 0, 0, 0, 0};
    float acc2[8] = {0, 0, 0, 0, 0, 0, 0, 0};
    int p = s;
    for (; p + 3 < e; p += 4) {
        int c0 = scol[p + half];
        int c1 = scol[p + 2 + half];
        u16x8 v0 = *reinterpret_cast<const u16x8*>(P + (size_t)c0 * DD + l32 * 8);
        u16x8 v1 = *reinterpret_cast<const u16x8*>(P + (size_t)c1 * DD + l32 * 8);
#pragma unroll
        for (int i = 0; i < 8; ++i) {
            acc[i] += bf2f(v0[i]);
            acc2[i] += bf2f(v1[i]);
        }
    }
    for (; p + 1 < e; p += 2) {
        int c0 = scol[p + half];
        u16x8 v0 = *reinterpret_cast<const u16x8*>(P + (size_t)c0 * DD + l32 * 8);
#pragma unroll
        for (int i = 0; i < 8; ++i) acc[i] += bf2f(v0[i]);
    }
    if (p < e && half == 0) {   // single leftover neighbor
        int c0 = scol[p];
        u16x8 v0 = *reinterpret_cast<const u16x8*>(P + (size_t)c0 * DD + l32 * 8);
#pragma unroll
        for (int i = 0; i < 8; ++i) acc2[i] += bf2f(v0[i]);
    }
    float rc = recip[node];
    u16x8 q = *reinterpret_cast<const u16x8*>(Q + (size_t)node * DD + l32 * 8);
    float4 b0 = *reinterpret_cast<const float4*>(b + l32 * 8);
    float4 b1 = *reinterpret_cast<const float4*>(b + l32 * 8 + 4);
    float bb[8] = {b0.x, b0.y, b0.z, b0.w, b1.x, b1.y, b1.z, b1.w};
    u16x8 o;
#pragma unroll
    for (int i = 0; i < 8; ++i) {
        float t = acc[i] + acc2[i];
        t += __shfl_xor(t, 32);
        t = t * rc + bf2f(q[i]) + bb[i];
        if (RELU) t = fmaxf(t, 0.0f);
        o[i] = f2bf(t);
    }
    if (half == 0)
        *reinterpret_cast<u16x8*>(out + (size_t)node * DD + l32 * 8) = o;
}

// ---------------------------------------------------------------------------
// Predictor: 512 threads = 8 waves, 128 queries/block.
// Gather: 16 threads/row x 4 steps (parallel, 16B loads), swizzled LDS.
// GEMM: cooperative N-split, wave w owns cols w*32..w*32+31 (2 nt).
__global__ __launch_bounds__(512, 4) void k_pred(const int* __restrict__ edges,
                                                 const unsigned short* __restrict__ x2,
                                                 const unsigned short* __restrict__ Wp1p,
                                                 const float* __restrict__ bp1,
                                                 const float* __restrict__ Wp2,
                                                 const float* __restrict__ bp2,
                                                 float* __restrict__ out) {
    __shared__ unsigned short sh[128 * 256];   // 64KB bf16 h tile, swizzled
    const int tid = threadIdx.x;
    const int wave = tid >> 6;
    const int lane = tid & 63;
    const int q0 = blockIdx.x * 128;

    const int grow = tid >> 4;         // 0..31
    const int t16 = tid & 15;
#pragma unroll
    for (int s = 0; s < 4; ++s) {
        int r = s * 32 + grow;
        int q = q0 + r;
        u16x8 p0 = {0, 0, 0, 0, 0, 0, 0, 0};
        u16x8 p1 = {0, 0, 0, 0, 0, 0, 0, 0};
        if (q < NQ) {
            int a = edges[q];
            int c = edges[NQ + q];
            const unsigned short* pa = x2 + (size_t)a * DD + t16 * 16;
            const unsigned short* pc = x2 + (size_t)c * DD + t16 * 16;
            u16x8 ua0 = *reinterpret_cast<const u16x8*>(pa);
            u16x8 ua1 = *reinterpret_cast<const u16x8*>(pa + 8);
            u16x8 uc0 = *reinterpret_cast<const u16x8*>(pc);
            u16x8 uc1 = *reinterpret_cast<const u16x8*>(pc + 8);
#pragma unroll
            for (int i = 0; i < 8; ++i) {
                p0[i] = f2bf(bf2f(ua0[i]) * bf2f(uc0[i]));
                p1[i] = f2bf(bf2f(ua1[i]) * bf2f(uc1[i]));
            }
        }
        int swz = (r & 7) << 3;
        *reinterpret_cast<u16x8*>(&sh[r * 256 + ((t16 * 16) ^ swz)]) = p0;
        *reinterpret_cast<u16x8*>(&sh[r * 256 + ((t16 * 16 + 8) ^ swz)]) = p1;
    }
    __syncthreads();

    f32x4 acc[8][2];
#pragma unroll
    for (int m = 0; m < 8; ++m)
#pragma unroll
        for (int n = 0; n < 2; ++n) acc[m][n] = {0, 0, 0, 0};

    const int akoff = (lane >> 4) * 8;
    const int arl = lane & 15;
    for (int kt = 0; kt < 8; ++kt) {
        bf16x8 af[8];
#pragma unroll
        for (int m = 0; m < 8; ++m) {
            int row = m * 16 + arl;
            af[m] = *reinterpret_cast<const bf16x8*>(
                &sh[row * 256 + ((kt * 32 + akoff) ^ ((row & 7) << 3))]);
        }
#pragma unroll
        for (int ntl = 0; ntl < 2; ++ntl) {
            int nt = wave * 2 + ntl;
            bf16x8 bfrag = *reinterpret_cast<const bf16x8*>(
                Wp1p + ((size_t)((kt * 16 + nt) * 64 + lane)) * 8);
#pragma unroll
            for (int m = 0; m < 8; ++m)
                acc[m][ntl] = __builtin_amdgcn_mfma_f32_16x16x32_bf16(af[m], bfrag, acc[m][ntl], 0, 0, 0);
        }
    }

    float rs[8][4];
#pragma unroll
    for (int m = 0; m < 8; ++m)
#pragma unroll
        for (int j = 0; j < 4; ++j) rs[m][j] = 0.0f;
#pragma unroll
    for (int ntl = 0; ntl < 2; ++ntl) {
        int n = (wave * 2 + ntl) * 16 + (lane & 15);
        float bias = bp1[n];
        float w2 = Wp2[n];
#pragma unroll
        for (int m = 0; m < 8; ++m)
#pragma unroll
            for (int j = 0; j < 4; ++j)
                rs[m][j] += fmaxf(acc[m][ntl][j] + bias, 0.0f) * w2;
    }
#pragma unroll
    for (int msk = 1; msk < 16; msk <<= 1) {
#pragma unroll
        for (int m = 0; m < 8; ++m)
#pragma unroll
            for (int j = 0; j < 4; ++j) rs[m][j] += __shfl_xor(rs[m][j], msk);
    }

    float* psum = reinterpret_cast<float*>(sh);   // aliases sh, dead after GEMM
    __syncthreads();
    if ((lane & 15) == 0) {
        int rg = (lane >> 4) * 4;
#pragma unroll
        for (int m = 0; m < 8; ++m)
#pragma unroll
            for (int j = 0; j < 4; ++j)
                psum[wave * 128 + m * 16 + rg + j] = rs[m][j];
    }
    __syncthreads();

    if (tid < 128) {
        int q = q0 + tid;
        if (q < NQ) {
            float z = bp2[0];
#pragma unroll
            for (int w = 0; w < 8; ++w) z += psum[w * 128 + tid];
            out[q] = 1.0f / (1.0f + expf(-z));
        }
    }
}

// ---------------------------------------------------------------------------
extern "C" void kernel_launch(void* const* d_in, const int* in_sizes, int n_in,
                              void* d_out, int out_size, void* d_ws, size_t ws_size,
                              hipStream_t stream) {
    const int*   adj_row = (const int*)d_in[0];
    const int*   adj_col = (const int*)d_in[1];
    const int*   edges   = (const int*)d_in[2];
    const float* emb     = (const float*)d_in[3];
    const float* W1l     = (const float*)d_in[4];
    const float* b1      = (const float*)d_in[5];
    const float* W1r     = (const float*)d_in[6];
    const float* W2l     = (const float*)d_in[7];
    const float* b2      = (const float*)d_in[8];
    const float* W2r     = (const float*)d_in[9];
    const float* Wp1     = (const float*)d_in[10];
    const float* bp1     = (const float*)d_in[11];
    const float* Wp2     = (const float*)d_in[12];
    const float* bp2     = (const float*)d_in[13];
    float* out = (float*)d_out;

    const size_t featH = (size_t)NN * DD * 2;   // 10.24 MB
    const size_t packBytes = (size_t)DD * DD * 2;

    char* ws = (char*)d_ws;
    size_t off = 0;
    unsigned short* P  = (unsigned short*)(ws + off); off += featH;
    unsigned short* Q  = (unsigned short*)(ws + off); off += featH;
    unsigned short* x1 = (unsigned short*)(ws + off); off += featH;
    unsigned short* xh = (unsigned short*)(ws + off); off += featH;  // emb_bf16, later x2
    int*   deg    = (int*)(ws + off);   off += (size_t)NN * 4;
    int*   offs   = (int*)(ws + off);   off += (size_t)(NN + 1) * 4;
    int*   cursor = (int*)(ws + off);   off += (size_t)NN * 4;
    float* recip  = (float*)(ws + off); off += (size_t)NN * 4;
    int*   bsum   = (int*)(ws + off);   off += (size_t)NB * 4;
    int*   scol   = (int*)(ws + off);   off += (size_t)NE * 4;
    unsigned short* Wp1p = (unsigned short*)(ws + off); off += packBytes;
    unsigned short* pk[8];   // W1l,W1r,W2l,W2r x {hi,lo}
    for (int i = 0; i < 8; ++i) { pk[i] = (unsigned short*)(ws + off); off += packBytes; }

    const int MB4 = ((NN + 63) / 64) * 4;   // 313 M-blocks x 4 N-quarters

    // emb -> bf16, CSR build, weight packs
    k_cast<<<(NN * DD / 8 + 255) / 256, 256, 0, stream>>>(emb, xh);
    hipMemsetAsync(deg, 0, NN * 4, stream);
    k_deg<<<(NE + 255) / 256, 256, 0, stream>>>(adj_row, deg);
    k_scan1<<<NB, 256, 0, stream>>>(deg, offs, bsum);
    k_scan2<<<1, 256, 0, stream>>>(bsum);
    k_scan3<<<NB, 256, 0, stream>>>(deg, bsum, offs, cursor, recip);
    k_fill<<<(NE + 255) / 256, 256, 0, stream>>>(adj_row, adj_col, cursor, scol);
    k_packs<<<160, 256, 0, stream>>>(W1l, W1r, W2l, W2r, Wp1,
                                     pk[0], pk[2], pk[4], pk[6], Wp1p,
                                     pk[1], pk[3], pk[5], pk[7]);

    // Layer 1: P = emb@W1l, Q = emb@W1r; x1 = relu(mean_N(P) + Q + b1)
    k_lin<<<MB4, 256, 0, stream>>>(xh, pk[0], pk[1], pk[2], pk[3], P, Q);
    k_gath<1><<<(NN + 3) / 4, 256, 0, stream>>>(offs, scol, recip, P, Q, b1, x1);

    // Layer 2: P = x1@W2l, Q = x1@W2r; x2 = mean_N(P) + Q + b2 (reuses xh)
    unsigned short* x2 = xh;   // emb_bf16 dead after layer-1 k_lin
    k_lin<<<MB4, 256, 0, stream>>>(x1, pk[4], pk[5], pk[6], pk[7], P, Q);
    k_gath<0><<<(NN + 3) / 4, 256, 0, stream>>>(offs, scol, recip, P, Q, b2, x2);

    // Predictor (512-thread cooperative bf16 MFMA)
    k_pred<<<(NQ + 127) / 128, 512, 0, stream>>>(edges, x2, Wp1p, bp1, Wp2, bp2, out);
}

// Round 10
// 195.407 us; speedup vs baseline: 2.5694x; 1.0097x over previous
//
#include <hip/hip_runtime.h>
#include <cstddef>

// Problem constants (match reference)
constexpr int NN = 20000;    // nodes
constexpr int NE = 320000;   // edges
constexpr int NQ = 100000;   // queries
constexpr int DD = 256;      // feature dim
constexpr int NB = (NN + 255) / 256;   // scan blocks (79)

typedef __attribute__((ext_vector_type(8))) short bf16x8;
typedef __attribute__((ext_vector_type(4))) float f32x4;
typedef __attribute__((ext_vector_type(4))) unsigned short u16x4;
typedef __attribute__((ext_vector_type(8))) unsigned short u16x8;

__device__ inline unsigned short f2bf(float f) {
    union { float f; unsigned u; } v; v.f = f;
    unsigned r = v.u + 0x7fffu + ((v.u >> 16) & 1u);   // RNE
    return (unsigned short)(r >> 16);
}
__device__ inline float bf2f(unsigned short h) {
    union { unsigned u; float f; } t; t.u = ((unsigned)h) << 16;
    return t.f;
}

// ---------------------------------------------------------------------------
// Cast emb f32 -> bf16 (16B/thread) + zero deg (replaces hipMemsetAsync:
// the runtime fill kernel cost 43us/replay for an 80KB buffer).
__global__ __launch_bounds__(256) void k_cast(const float* __restrict__ x,
                                              unsigned short* __restrict__ y,
                                              int* __restrict__ deg) {
    int i = blockIdx.x * 256 + threadIdx.x;   // 8 elems per thread
    if (i < NN) deg[i] = 0;
    if (i >= NN * DD / 8) return;
    float4 f0 = *reinterpret_cast<const float4*>(x + (size_t)i * 8);
    float4 f1 = *reinterpret_cast<const float4*>(x + (size_t)i * 8 + 4);
    u16x8 o;
    o[0] = f2bf(f0.x); o[1] = f2bf(f0.y); o[2] = f2bf(f0.z); o[3] = f2bf(f0.w);
    o[4] = f2bf(f1.x); o[5] = f2bf(f1.y); o[6] = f2bf(f1.z); o[7] = f2bf(f1.w);
    *reinterpret_cast<u16x8*>(y + (size_t)i * 8) = o;
}

// ---------------------------------------------------------------------------
// Degree histogram (int): deg[row[e]] += 1
__global__ __launch_bounds__(256) void k_deg(const int* __restrict__ row,
                                             int* __restrict__ deg) {
    int e = blockIdx.x * 256 + threadIdx.x;
    if (e < NE) atomicAdd(&deg[row[e]], 1);
}

// Parallel scan, step 1: block-local exclusive scan + block sums.
__global__ __launch_bounds__(256) void k_scan1(const int* __restrict__ deg,
                                               int* __restrict__ offs,
                                               int* __restrict__ bsum) {
    __shared__ int wsum[4];
    const int tid = threadIdx.x, lane = tid & 63, wid = tid >> 6;
    int i = blockIdx.x * 256 + tid;
    int v = (i < NN) ? deg[i] : 0;
    int sc = v;
#pragma unroll
    for (int d = 1; d < 64; d <<= 1) {
        int t = __shfl_up(sc, d);
        if (lane >= d) sc += t;
    }
    if (lane == 63) wsum[wid] = sc;
    __syncthreads();
    int wpre = 0;
    for (int w = 0; w < wid; ++w) wpre += wsum[w];
    if (i < NN) offs[i] = wpre + sc - v;
    if (tid == 255) bsum[blockIdx.x] = wpre + sc;
}

// Step 2: exclusive scan over the NB block sums (single small block).
__global__ __launch_bounds__(256) void k_scan2(int* __restrict__ bsum) {
    __shared__ int wsum[4];
    const int tid = threadIdx.x, lane = tid & 63, wid = tid >> 6;
    int v = (tid < NB) ? bsum[tid] : 0;
    int sc = v;
#pragma unroll
    for (int d = 1; d < 64; d <<= 1) {
        int t = __shfl_up(sc, d);
        if (lane >= d) sc += t;
    }
    if (lane == 63) wsum[wid] = sc;
    __syncthreads();
    int wpre = 0;
    for (int w = 0; w < wid; ++w) wpre += wsum[w];
    if (tid < NB) bsum[tid] = wpre + sc - v;
}

// Step 3: add block prefix; emit cursor + recip; offs[NN] = NE.
__global__ __launch_bounds__(256) void k_scan3(const int* __restrict__ deg,
                                               const int* __restrict__ bsum,
                                               int* __restrict__ offs,
                                               int* __restrict__ cursor,
                                               float* __restrict__ recip) {
    int i = blockIdx.x * 256 + threadIdx.x;
    if (i < NN) {
        int o = offs[i] + bsum[i >> 8];
        offs[i] = o;
        cursor[i] = o;
        recip[i] = 1.0f / fmaxf((float)deg[i], 1.0f);
    }
    if (i == 0) offs[NN] = NE;
}

// Fill CSR adjacency: scol[cursor[row[e]]++] = col[e]
__global__ __launch_bounds__(256) void k_fill(const int* __restrict__ row,
                                              const int* __restrict__ col,
                                              int* __restrict__ cursor,
                                              int* __restrict__ scol) {
    int e = blockIdx.x * 256 + threadIdx.x;
    if (e < NE) {
        int r = row[e];
        int p = atomicAdd(&cursor[r], 1);
        scol[p] = col[e];
    }
}

// ---------------------------------------------------------------------------
// Pack 5 f32 256x256 matrices into bf16 MFMA B-fragment layout.
// m = 0..3: hi + lo split (W1l,W1r,W2l,W2r). m = 4: hi only (Wp1).
__global__ __launch_bounds__(256) void k_packs(
    const float* __restrict__ w0, const float* __restrict__ w1,
    const float* __restrict__ w2, const float* __restrict__ w3,
    const float* __restrict__ w4,
    unsigned short* __restrict__ h0, unsigned short* __restrict__ h1,
    unsigned short* __restrict__ h2, unsigned short* __restrict__ h3,
    unsigned short* __restrict__ h4,
    unsigned short* __restrict__ l0, unsigned short* __restrict__ l1,
    unsigned short* __restrict__ l2, unsigned short* __restrict__ l3) {
    int m = blockIdx.x >> 5;
    int idx = (blockIdx.x & 31) * 256 + threadIdx.x;   // 0..8191
    const float* W = (m == 0) ? w0 : (m == 1) ? w1 : (m == 2) ? w2 : (m == 3) ? w3 : w4;
    unsigned short* H = (m == 0) ? h0 : (m == 1) ? h1 : (m == 2) ? h2 : (m == 3) ? h3 : h4;
    unsigned short* L = (m == 0) ? l0 : (m == 1) ? l1 : (m == 2) ? l2 : (m == 3) ? l3 : nullptr;
    int t = idx >> 6, lane = idx & 63;
    int kt = t >> 4, nt = t & 15;
    int k0 = kt * 32 + (lane >> 4) * 8;
    int n = nt * 16 + (lane & 15);
    unsigned uh[4], ul[4];
#pragma unroll
    for (int i = 0; i < 4; ++i) {
        float fa = W[(size_t)(k0 + 2 * i) * DD + n];
        float fb = W[(size_t)(k0 + 2 * i + 1) * DD + n];
        unsigned short ha = f2bf(fa), hb = f2bf(fb);
        unsigned short la = f2bf(fa - bf2f(ha)), lb = f2bf(fb - bf2f(hb));
        uh[i] = (unsigned)ha | ((unsigned)hb << 16);
        ul[i] = (unsigned)la | ((unsigned)lb << 16);
    }
    *reinterpret_cast<uint4*>(H + (size_t)idx * 8) = make_uint4(uh[0], uh[1], uh[2], uh[3]);
    if (L)
        *reinterpret_cast<uint4*>(L + (size_t)idx * 8) = make_uint4(ul[0], ul[1], ul[2], ul[3]);
}

// ---------------------------------------------------------------------------
// Dense dual GEMM: P = A @ Wl, Q = A @ Wr (A exact bf16; weights hi+lo ->
// 2 MFMA terms each). Mean-aggregation is deferred to k_gath (linearity).
// Wave = one 16-row M-tile x 64 cols (N-quarter). Block = 4 waves = 64 rows.
// blockIdx = mblk*4 + nquarter.
__global__ __launch_bounds__(256) void k_lin(
    const unsigned short* __restrict__ A,
    const unsigned short* __restrict__ Wlh, const unsigned short* __restrict__ Wll,
    const unsigned short* __restrict__ Wrh, const unsigned short* __restrict__ Wrl,
    unsigned short* __restrict__ P, unsigned short* __restrict__ Q) {
    const int nq   = blockIdx.x & 3;
    const int mblk = blockIdx.x >> 2;
    const int wave = threadIdx.x >> 6;
    const int lane = threadIdx.x & 63;
    const int row0 = mblk * 64 + wave * 16;
    const int kcol = (lane >> 4) * 8;
    const int ar = min(row0 + (lane & 15), NN - 1);

    f32x4 accP[4], accQ[4];
#pragma unroll
    for (int nt = 0; nt < 4; ++nt) {
        accP[nt] = {0, 0, 0, 0};
        accQ[nt] = {0, 0, 0, 0};
    }

#pragma unroll 2
    for (int kt = 0; kt < 8; ++kt) {
        bf16x8 a1 = *reinterpret_cast<const bf16x8*>(A + (size_t)ar * DD + kt * 32 + kcol);
#pragma unroll
        for (int nt = 0; nt < 4; ++nt) {
            const size_t fo = ((size_t)((kt * 16 + nq * 4 + nt) * 64 + lane)) * 8;
            bf16x8 blh = *reinterpret_cast<const bf16x8*>(Wlh + fo);
            bf16x8 bll = *reinterpret_cast<const bf16x8*>(Wll + fo);
            bf16x8 brh = *reinterpret_cast<const bf16x8*>(Wrh + fo);
            bf16x8 brl = *reinterpret_cast<const bf16x8*>(Wrl + fo);
            accP[nt] = __builtin_amdgcn_mfma_f32_16x16x32_bf16(a1, blh, accP[nt], 0, 0, 0);
            accP[nt] = __builtin_amdgcn_mfma_f32_16x16x32_bf16(a1, bll, accP[nt], 0, 0, 0);
            accQ[nt] = __builtin_amdgcn_mfma_f32_16x16x32_bf16(a1, brh, accQ[nt], 0, 0, 0);
            accQ[nt] = __builtin_amdgcn_mfma_f32_16x16x32_bf16(a1, brl, accQ[nt], 0, 0, 0);
        }
    }

    // Store. acc[nt][j]: row = (lane>>4)*4+j, col = (nq*4+nt)*16 + (lane&15).
    const int n0 = lane & 15;
    const int rg = (lane >> 4) * 4;
#pragma unroll
    for (int nt = 0; nt < 4; ++nt) {
        int n = (nq * 4 + nt) * 16 + n0;
#pragma unroll
        for (int j = 0; j < 4; ++j) {
            int r = row0 + rg + j;
            if (r < NN) {
                P[(size_t)r * DD + n] = f2bf(accP[nt][j]);
                Q[(size_t)r * DD + n] = f2bf(accQ[nt][j]);
            }
        }
    }
}

// ---------------------------------------------------------------------------
// Gather + epilogue: out[i] = [relu]( recip[i]*sum_{c in N(i)} P[c,:]
//                                     + Q[i,:] + b )   (bf16 out)
// One wave per node; 2 neighbors in parallel (lane>>5), 16B loads.
template <int RELU>
__global__ __launch_bounds__(256) void k_gath(const int* __restrict__ offs,
                                              const int* __restrict__ scol,
                                              const float* __restrict__ recip,
                                              const unsigned short* __restrict__ P,
                                              const unsigned short* __restrict__ Q,
                                              const float* __restrict__ b,
                                              unsigned short* __restrict__ out) {
    int node = blockIdx.x * 4 + (threadIdx.x >> 6);
    int lane = threadIdx.x & 63;
    if (node >= NN) return;
    int s = offs[node];
    int e = offs[node + 1];
    const int half = lane >> 5;
    const int l32 = lane & 31;
    float acc[8] = {0, 0, 0, 0, 0, 0, 0, 0};
    float acc2[8] = {0, 0, 0, 0, 0, 0, 0, 0};
    int p = s;
    for (; p + 3 < e; p += 4) {
        int c0 = scol[p + half];
        int c1 = scol[p + 2 + half];
        u16x8 v0 = *reinterpret_cast<const u16x8*>(P + (size_t)c0 * DD + l32 * 8);
        u16x8 v1 = *reinterpret_cast<const u16x8*>(P + (size_t)c1 * DD + l32 * 8);
#pragma unroll
        for (int i = 0; i < 8; ++i) {
            acc[i] += bf2f(v0[i]);
            acc2[i] += bf2f(v1[i]);
        }
    }
    for (; p + 1 < e; p += 2) {
        int c0 = scol[p + half];
        u16x8 v0 = *reinterpret_cast<const u16x8*>(P + (size_t)c0 * DD + l32 * 8);
#pragma unroll
        for (int i = 0; i < 8; ++i) acc[i] += bf2f(v0[i]);
    }
    if (p < e && half == 0) {   // single leftover neighbor
        int c0 = scol[p];
        u16x8 v0 = *reinterpret_cast<const u16x8*>(P + (size_t)c0 * DD + l32 * 8);
#pragma unroll
        for (int i = 0; i < 8; ++i) acc2[i] += bf2f(v0[i]);
    }
    float rc = recip[node];
    u16x8 q = *reinterpret_cast<const u16x8*>(Q + (size_t)node * DD + l32 * 8);
    float4 b0 = *reinterpret_cast<const float4*>(b + l32 * 8);
    float4 b1 = *reinterpret_cast<const float4*>(b + l32 * 8 + 4);
    float bb[8] = {b0.x, b0.y, b0.z, b0.w, b1.x, b1.y, b1.z, b1.w};
    u16x8 o;
#pragma unroll
    for (int i = 0; i < 8; ++i) {
        float t = acc[i] + acc2[i];
        t += __shfl_xor(t, 32);
        t = t * rc + bf2f(q[i]) + bb[i];
        if (RELU) t = fmaxf(t, 0.0f);
        o[i] = f2bf(t);
    }
    if (half == 0)
        *reinterpret_cast<u16x8*>(out + (size_t)node * DD + l32 * 8) = o;
}

// ---------------------------------------------------------------------------
// Predictor: 512 threads = 8 waves, 128 queries/block.
// Gather: 16 threads/row x 4 steps (parallel, 16B loads), swizzled LDS.
// GEMM: cooperative N-split, wave w owns cols w*32..w*32+31 (2 nt).
__global__ __launch_bounds__(512, 4) void k_pred(const int* __restrict__ edges,
                                                 const unsigned short* __restrict__ x2,
                                                 const unsigned short* __restrict__ Wp1p,
                                                 const float* __restrict__ bp1,
                                                 const float* __restrict__ Wp2,
                                                 const float* __restrict__ bp2,
                                                 float* __restrict__ out) {
    __shared__ unsigned short sh[128 * 256];   // 64KB bf16 h tile, swizzled
    const int tid = threadIdx.x;
    const int wave = tid >> 6;
    const int lane = tid & 63;
    const int q0 = blockIdx.x * 128;

    const int grow = tid >> 4;         // 0..31
    const int t16 = tid & 15;
#pragma unroll
    for (int s = 0; s < 4; ++s) {
        int r = s * 32 + grow;
        int q = q0 + r;
        u16x8 p0 = {0, 0, 0, 0, 0, 0, 0, 0};
        u16x8 p1 = {0, 0, 0, 0, 0, 0, 0, 0};
        if (q < NQ) {
            int a = edges[q];
            int c = edges[NQ + q];
            const unsigned short* pa = x2 + (size_t)a * DD + t16 * 16;
            const unsigned short* pc = x2 + (size_t)c * DD + t16 * 16;
            u16x8 ua0 = *reinterpret_cast<const u16x8*>(pa);
            u16x8 ua1 = *reinterpret_cast<const u16x8*>(pa + 8);
            u16x8 uc0 = *reinterpret_cast<const u16x8*>(pc);
            u16x8 uc1 = *reinterpret_cast<const u16x8*>(pc + 8);
#pragma unroll
            for (int i = 0; i < 8; ++i) {
                p0[i] = f2bf(bf2f(ua0[i]) * bf2f(uc0[i]));
                p1[i] = f2bf(bf2f(ua1[i]) * bf2f(uc1[i]));
            }
        }
        int swz = (r & 7) << 3;
        *reinterpret_cast<u16x8*>(&sh[r * 256 + ((t16 * 16) ^ swz)]) = p0;
        *reinterpret_cast<u16x8*>(&sh[r * 256 + ((t16 * 16 + 8) ^ swz)]) = p1;
    }
    __syncthreads();

    f32x4 acc[8][2];
#pragma unroll
    for (int m = 0; m < 8; ++m)
#pragma unroll
        for (int n = 0; n < 2; ++n) acc[m][n] = {0, 0, 0, 0};

    const int akoff = (lane >> 4) * 8;
    const int arl = lane & 15;
    for (int kt = 0; kt < 8; ++kt) {
        bf16x8 af[8];
#pragma unroll
        for (int m = 0; m < 8; ++m) {
            int row = m * 16 + arl;
            af[m] = *reinterpret_cast<const bf16x8*>(
                &sh[row * 256 + ((kt * 32 + akoff) ^ ((row & 7) << 3))]);
        }
#pragma unroll
        for (int ntl = 0; ntl < 2; ++ntl) {
            int nt = wave * 2 + ntl;
            bf16x8 bfrag = *reinterpret_cast<const bf16x8*>(
                Wp1p + ((size_t)((kt * 16 + nt) * 64 + lane)) * 8);
#pragma unroll
            for (int m = 0; m < 8; ++m)
                acc[m][ntl] = __builtin_amdgcn_mfma_f32_16x16x32_bf16(af[m], bfrag, acc[m][ntl], 0, 0, 0);
        }
    }

    float rs[8][4];
#pragma unroll
    for (int m = 0; m < 8; ++m)
#pragma unroll
        for (int j = 0; j < 4; ++j) rs[m][j] = 0.0f;
#pragma unroll
    for (int ntl = 0; ntl < 2; ++ntl) {
        int n = (wave * 2 + ntl) * 16 + (lane & 15);
        float bias = bp1[n];
        float w2 = Wp2[n];
#pragma unroll
        for (int m = 0; m < 8; ++m)
#pragma unroll
            for (int j = 0; j < 4; ++j)
                rs[m][j] += fmaxf(acc[m][ntl][j] + bias, 0.0f) * w2;
    }
#pragma unroll
    for (int msk = 1; msk < 16; msk <<= 1) {
#pragma unroll
        for (int m = 0; m < 8; ++m)
#pragma unroll
            for (int j = 0; j < 4; ++j) rs[m][j] += __shfl_xor(rs[m][j], msk);
    }

    float* psum = reinterpret_cast<float*>(sh);   // aliases sh, dead after GEMM
    __syncthreads();
    if ((lane & 15) == 0) {
        int rg = (lane >> 4) * 4;
#pragma unroll
        for (int m = 0; m < 8; ++m)
#pragma unroll
            for (int j = 0; j < 4; ++j)
                psum[wave * 128 + m * 16 + rg + j] = rs[m][j];
    }
    __syncthreads();

    if (tid < 128) {
        int q = q0 + tid;
        if (q < NQ) {
            float z = bp2[0];
#pragma unroll
            for (int w = 0; w < 8; ++w) z += psum[w * 128 + tid];
            out[q] = 1.0f / (1.0f + expf(-z));
        }
    }
}

// ---------------------------------------------------------------------------
extern "C" void kernel_launch(void* const* d_in, const int* in_sizes, int n_in,
                              void* d_out, int out_size, void* d_ws, size_t ws_size,
                              hipStream_t stream) {
    const int*   adj_row = (const int*)d_in[0];
    const int*   adj_col = (const int*)d_in[1];
    const int*   edges   = (const int*)d_in[2];
    const float* emb     = (const float*)d_in[3];
    const float* W1l     = (const float*)d_in[4];
    const float* b1      = (const float*)d_in[5];
    const float* W1r     = (const float*)d_in[6];
    const float* W2l     = (const float*)d_in[7];
    const float* b2      = (const float*)d_in[8];
    const float* W2r     = (const float*)d_in[9];
    const float* Wp1     = (const float*)d_in[10];
    const float* bp1     = (const float*)d_in[11];
    const float* Wp2     = (const float*)d_in[12];
    const float* bp2     = (const float*)d_in[13];
    float* out = (float*)d_out;

    const size_t featH = (size_t)NN * DD * 2;   // 10.24 MB
    const size_t packBytes = (size_t)DD * DD * 2;

    char* ws = (char*)d_ws;
    size_t off = 0;
    unsigned short* P  = (unsigned short*)(ws + off); off += featH;
    unsigned short* Q  = (unsigned short*)(ws + off); off += featH;
    unsigned short* x1 = (unsigned short*)(ws + off); off += featH;
    unsigned short* xh = (unsigned short*)(ws + off); off += featH;  // emb_bf16, later x2
    int*   deg    = (int*)(ws + off);   off += (size_t)NN * 4;
    int*   offs   = (int*)(ws + off);   off += (size_t)(NN + 1) * 4;
    int*   cursor = (int*)(ws + off);   off += (size_t)NN * 4;
    float* recip  = (float*)(ws + off); off += (size_t)NN * 4;
    int*   bsum   = (int*)(ws + off);   off += (size_t)NB * 4;
    int*   scol   = (int*)(ws + off);   off += (size_t)NE * 4;
    unsigned short* Wp1p = (unsigned short*)(ws + off); off += packBytes;
    unsigned short* pk[8];   // W1l,W1r,W2l,W2r x {hi,lo}
    for (int i = 0; i < 8; ++i) { pk[i] = (unsigned short*)(ws + off); off += packBytes; }

    const int MB4 = ((NN + 63) / 64) * 4;   // 313 M-blocks x 4 N-quarters

    // emb -> bf16 + deg zero (fused; no runtime fill kernel), CSR, packs
    k_cast<<<(NN * DD / 8 + 255) / 256, 256, 0, stream>>>(emb, xh, deg);
    k_deg<<<(NE + 255) / 256, 256, 0, stream>>>(adj_row, deg);
    k_scan1<<<NB, 256, 0, stream>>>(deg, offs, bsum);
    k_scan2<<<1, 256, 0, stream>>>(bsum);
    k_scan3<<<NB, 256, 0, stream>>>(deg, bsum, offs, cursor, recip);
    k_fill<<<(NE + 255) / 256, 256, 0, stream>>>(adj_row, adj_col, cursor, scol);
    k_packs<<<160, 256, 0, stream>>>(W1l, W1r, W2l, W2r, Wp1,
                                     pk[0], pk[2], pk[4], pk[6], Wp1p,
                                     pk[1], pk[3], pk[5], pk[7]);

    // Layer 1: P = emb@W1l, Q = emb@W1r; x1 = relu(mean_N(P) + Q + b1)
    k_lin<<<MB4, 256, 0, stream>>>(xh, pk[0], pk[1], pk[2], pk[3], P, Q);
    k_gath<1><<<(NN + 3) / 4, 256, 0, stream>>>(offs, scol, recip, P, Q, b1, x1);

    // Layer 2: P = x1@W2l, Q = x1@W2r; x2 = mean_N(P) + Q + b2 (reuses xh)
    unsigned short* x2 = xh;   // emb_bf16 dead after layer-1 k_lin
    k_lin<<<MB4, 256, 0, stream>>>(x1, pk[4], pk[5], pk[6], pk[7], P, Q);
    k_gath<0><<<(NN + 3) / 4, 256, 0, stream>>>(offs, scol, recip, P, Q, b2, x2);

    // Predictor (512-thread cooperative bf16 MFMA)
    k_pred<<<(NQ + 127) / 128, 512, 0, stream>>>(edges, x2, Wp1p, bp1, Wp2, bp2, out);
}